// Round 6
// baseline (1236.822 us; speedup 1.0000x reference)
//
#include <hip/hip_runtime.h>
#include <hip/hip_bf16.h>
#include <math.h>

// ---------------------------------------------------------------------------
// 3-layer GCN: per layer  h' = Dis (A+I) Dis (h W) + b   (Dis = D^{-1/2})
// CSR build is bucketed to kill write amplification:
//   bhist(bucket histo) -> bscan -> bin(append streams) ->
//   cntB(LDS per-node count) -> scan(ptr,dis) -> fill2(LDS cursors)
// then gemm -> aggregate(+bias,+relu) x3 -> log_softmax
// Bucket = 256 consecutive dst nodes; NB = ceil(N/256) (<=512 assumed).
// ---------------------------------------------------------------------------

// ---- bucket histogram: 512-entry LDS histo per block, merged by atomics ----
__global__ __launch_bounds__(256) void k_bhist(const int* __restrict__ col, int E,
                                               int NB, int* __restrict__ bhist) {
    __shared__ int h[512];
    for (int j = threadIdx.x; j < 512; j += 256) h[j] = 0;
    __syncthreads();
    int chunk = (E + gridDim.x - 1) / gridDim.x;
    int lo = blockIdx.x * chunk;
    int hi = min(lo + chunk, E);
    for (int i = lo + threadIdx.x; i < hi; i += 256)
        atomicAdd(&h[col[i] >> 8], 1);
    __syncthreads();
    for (int j = threadIdx.x; j < NB; j += 256) {
        int v = h[j];
        if (v) atomicAdd(&bhist[j], v);
    }
}

// ---- exclusive scan of bucket counts (NB <= 512), one block ----
__global__ __launch_bounds__(512) void k_bscan(const int* __restrict__ bhist,
                                               int NB, int E,
                                               int* __restrict__ bbase,
                                               int* __restrict__ bcur) {
    __shared__ int sm[512];
    int t = threadIdx.x;
    int v = (t < NB) ? bhist[t] : 0;
    sm[t] = v;
    __syncthreads();
    for (int off = 1; off < 512; off <<= 1) {
        int u = (t >= off) ? sm[t - off] : 0;
        __syncthreads();
        sm[t] += u;
        __syncthreads();
    }
    if (t < NB) {
        int ex = sm[t] - v;
        bbase[t] = ex;
        bcur[t] = ex;
    }
    if (t == 0) bbase[NB] = E;
}

// ---- bin edges into bucket-major staging (append streams) ----
__global__ void k_bin(const int* __restrict__ row, const int* __restrict__ col,
                      int E, int* __restrict__ bcur, uint2* __restrict__ binned) {
    int i = blockIdx.x * blockDim.x + threadIdx.x;
    if (i < E) {
        int r = row[i], c = col[i];
        int p = atomicAdd(&bcur[c >> 8], 1);
        binned[p] = make_uint2((unsigned)r, (unsigned)c);
    }
}

// ---- per-node counts from binned data, LDS histogram per bucket ----
__global__ __launch_bounds__(256) void k_cntB(const uint2* __restrict__ binned,
                                              const int* __restrict__ bbase,
                                              int N, int* __restrict__ cnt) {
    int b = blockIdx.x, t = threadIdx.x;
    __shared__ int sc[256];
    sc[t] = 0;
    __syncthreads();
    int lo = bbase[b], hi = bbase[b + 1];
    for (int i = lo + t; i < hi; i += 256)
        atomicAdd(&sc[binned[i].y & 255], 1);
    __syncthreads();
    int node = b * 256 + t;
    if (node < N) cnt[node] = sc[t];
}

// ---- parallel scan, stage 1: per-block (1024 elems) sums ----
__global__ __launch_bounds__(256) void k_bsum(const int* __restrict__ cnt, int N,
                                              int* __restrict__ bsum) {
    int t = threadIdx.x;
    int base = blockIdx.x * 1024 + t * 4;
    int s = 0;
    if (base + 3 < N) {
        int4 v = *(const int4*)(cnt + base);
        s = v.x + v.y + v.z + v.w;
    } else {
        for (int j = 0; j < 4; ++j)
            if (base + j < N) s += cnt[base + j];
    }
#pragma unroll
    for (int off = 32; off; off >>= 1) s += __shfl_xor(s, off);
    __shared__ int ws[4];
    int lane = t & 63, w = t >> 6;
    if (lane == 0) ws[w] = s;
    __syncthreads();
    if (t == 0) bsum[blockIdx.x] = ws[0] + ws[1] + ws[2] + ws[3];
}

// ---- stage 2: exclusive scan of block sums (B <= 128), one tiny block ----
__global__ __launch_bounds__(128) void k_sbsum(int* __restrict__ bsum, int B) {
    __shared__ int sm[128];
    int t = threadIdx.x;
    int v = (t < B) ? bsum[t] : 0;
    sm[t] = v;
    __syncthreads();
    for (int off = 1; off < 128; off <<= 1) {
        int u = (t >= off) ? sm[t - off] : 0;
        __syncthreads();
        sm[t] += u;
        __syncthreads();
    }
    if (t < B) bsum[t] = sm[t] - v;  // exclusive prefix
}

// ---- stage 3: per-block exclusive scan + write ptr/dis ----
__global__ __launch_bounds__(256) void k_wptr(const int* __restrict__ cnt,
                                              const int* __restrict__ bsum, int N,
                                              int* __restrict__ ptr,
                                              float* __restrict__ dis) {
    int t = threadIdx.x;
    int base = blockIdx.x * 1024 + t * 4;
    int c[4];
    int s = 0;
    if (base + 3 < N) {
        int4 v = *(const int4*)(cnt + base);
        c[0] = v.x; c[1] = v.y; c[2] = v.z; c[3] = v.w;
        s = v.x + v.y + v.z + v.w;
    } else {
#pragma unroll
        for (int j = 0; j < 4; ++j) {
            c[j] = (base + j < N) ? cnt[base + j] : 0;
            s += c[j];
        }
    }
    int lane = t & 63, w = t >> 6;
    int incl = s;
#pragma unroll
    for (int off = 1; off < 64; off <<= 1) {
        int u = __shfl_up(incl, off);
        if (lane >= off) incl += u;
    }
    __shared__ int wsum[4];
    if (lane == 63) wsum[w] = incl;
    __syncthreads();
    int run = bsum[blockIdx.x] + (incl - s);
    for (int j = 0; j < w; ++j) run += wsum[j];
#pragma unroll
    for (int j = 0; j < 4; ++j) {
        int i = base + j;
        if (i < N) {
            ptr[i] = run;
            dis[i] = rsqrtf((float)(c[j] + 1));  // +1 self-loop
            run += c[j];
        }
    }
}

// ---- CSR fill from binned data with LDS cursors (L2-local esrc writes) ----
__global__ __launch_bounds__(256) void k_fill2(const uint2* __restrict__ binned,
                                               const int* __restrict__ bbase,
                                               const int* __restrict__ ptr, int N,
                                               int* __restrict__ esrc) {
    int b = blockIdx.x, t = threadIdx.x;
    __shared__ int lc[256];
    int node = b * 256 + t;
    lc[t] = (node < N) ? ptr[node] : 0;
    __syncthreads();
    int lo = bbase[b], hi = bbase[b + 1];
    for (int i = lo + t; i < hi; i += 256) {
        uint2 e = binned[i];
        int p = atomicAdd(&lc[e.y & 255], 1);
        esrc[p] = (int)e.x;
    }
}

// ---- GEMM: Y[M][128] = X[M][128] @ W[128][128], no bias (added post-agg) ----
__global__ __launch_bounds__(256) void k_gemm128(const float* __restrict__ X,
                                                 const float* __restrict__ W,
                                                 float* __restrict__ Y, int M) {
    __shared__ float wsm[64 * 128];  // 32 KB: W rows [kp*64, kp*64+64)
    __shared__ float xs[64 * 68];    // 17 KB: X tile [64 rows][64 k], pad 68
    int t = threadIdx.x;
    int row0 = blockIdx.x * 64;
    int cg = t & 15, rg = t >> 4;
    float acc[4][8];
#pragma unroll
    for (int a = 0; a < 4; ++a)
#pragma unroll
        for (int b = 0; b < 8; ++b) acc[a][b] = 0.f;

    for (int kp = 0; kp < 2; ++kp) {
        const float4* W4 = (const float4*)W;
        float4* wd = (float4*)wsm;
#pragma unroll
        for (int i = 0; i < 8; ++i) {
            int idx = t + i * 256;
            wd[idx] = W4[kp * 2048 + idx];
        }
        const float4* X4 = (const float4*)X;
#pragma unroll
        for (int i = 0; i < 4; ++i) {
            int idx = t + i * 256;
            int r = idx >> 4, c4 = idx & 15;
            float4 v = {0.f, 0.f, 0.f, 0.f};
            if (row0 + r < M) v = X4[(size_t)(row0 + r) * 32 + kp * 16 + c4];
            float* dst = &xs[r * 68 + c4 * 4];
            dst[0] = v.x; dst[1] = v.y; dst[2] = v.z; dst[3] = v.w;
        }
        __syncthreads();
#pragma unroll 4
        for (int k = 0; k < 64; ++k) {
            float a0 = xs[(rg * 4 + 0) * 68 + k];
            float a1 = xs[(rg * 4 + 1) * 68 + k];
            float a2 = xs[(rg * 4 + 2) * 68 + k];
            float a3 = xs[(rg * 4 + 3) * 68 + k];
            const float* wr = &wsm[k * 128 + cg * 8];
            float4 w0 = *(const float4*)wr;
            float4 w1 = *(const float4*)(wr + 4);
            float wv[8] = {w0.x, w0.y, w0.z, w0.w, w1.x, w1.y, w1.z, w1.w};
#pragma unroll
            for (int b = 0; b < 8; ++b) {
                acc[0][b] = fmaf(a0, wv[b], acc[0][b]);
                acc[1][b] = fmaf(a1, wv[b], acc[1][b]);
                acc[2][b] = fmaf(a2, wv[b], acc[2][b]);
                acc[3][b] = fmaf(a3, wv[b], acc[3][b]);
            }
        }
        __syncthreads();
    }
#pragma unroll
    for (int a = 0; a < 4; ++a) {
        int r = row0 + rg * 4 + a;
        if (r < M) {
            float4* dst = (float4*)&Y[(size_t)r * 128 + cg * 8];
            float4 o0 = {acc[a][0], acc[a][1], acc[a][2], acc[a][3]};
            float4 o1 = {acc[a][4], acc[a][5], acc[a][6], acc[a][7]};
            dst[0] = o0;
            dst[1] = o1;
        }
    }
}

// ---- GEMM: Y[M][40] = X[M][128] @ W[128][40] ----
__global__ __launch_bounds__(320) void k_gemm40(const float* __restrict__ X,
                                                const float* __restrict__ W,
                                                float* __restrict__ Y, int M) {
    __shared__ float wsm[128 * 40];  // 20 KB
    __shared__ float xs[64 * 133];   // 34 KB
    int t = threadIdx.x;
    int row0 = blockIdx.x * 64;
    for (int idx = t; idx < 128 * 40; idx += 320) wsm[idx] = W[idx];
    for (int idx = t; idx < 64 * 128; idx += 320) {
        int r = idx >> 7, c = idx & 127;
        xs[r * 133 + c] = (row0 + r < M) ? X[(size_t)(row0 + r) * 128 + c] : 0.f;
    }
    __syncthreads();
    int lane = t & 63, cg = t >> 6;  // cg 0..4
    float acc[8];
#pragma unroll
    for (int b = 0; b < 8; ++b) acc[b] = 0.f;
#pragma unroll 4
    for (int k = 0; k < 128; ++k) {
        float a = xs[lane * 133 + k];
        const float* wr = &wsm[k * 40 + cg * 8];
        float4 w0 = *(const float4*)wr;
        float4 w1 = *(const float4*)(wr + 4);
        acc[0] = fmaf(a, w0.x, acc[0]); acc[1] = fmaf(a, w0.y, acc[1]);
        acc[2] = fmaf(a, w0.z, acc[2]); acc[3] = fmaf(a, w0.w, acc[3]);
        acc[4] = fmaf(a, w1.x, acc[4]); acc[5] = fmaf(a, w1.y, acc[5]);
        acc[6] = fmaf(a, w1.z, acc[6]); acc[7] = fmaf(a, w1.w, acc[7]);
    }
    int r = row0 + lane;
    if (r < M) {
        float4* dst = (float4*)&Y[(size_t)r * 40 + cg * 8];
        float4 o0 = {acc[0], acc[1], acc[2], acc[3]};
        float4 o1 = {acc[4], acc[5], acc[6], acc[7]};
        dst[0] = o0;
        dst[1] = o1;
    }
}

// ---- aggregation, 128 features: one wave per node, lane owns float2 ----
__global__ __launch_bounds__(256) void k_agg128(const float* __restrict__ h,
                                                const float* __restrict__ dis,
                                                const int* __restrict__ ptr,
                                                const int* __restrict__ cnt,
                                                const int* __restrict__ esrc,
                                                const float* __restrict__ bias,
                                                float* __restrict__ out,
                                                int relu, int N) {
    int node = blockIdx.x * 4 + (threadIdx.x >> 6);
    if (node >= N) return;
    int lane = threadIdx.x & 63;
    float di = dis[node];
    const float2* hrow = (const float2*)(h + (size_t)node * 128);
    float2 self = hrow[lane];
    float w = di * di;
    float ax = self.x * w, ay = self.y * w;
    int start = ptr[node], c = cnt[node];
    for (int base = 0; base < c; base += 64) {
        int m = min(64, c - base);
        int e = 0;
        float dsl = 0.f;
        if (lane < m) {
            e = esrc[start + base + lane];
            dsl = dis[e];
        }
        int j = 0;
        for (; j + 2 <= m; j += 2) {
            int sA = __shfl(e, j), sB = __shfl(e, j + 1);
            float scA = __shfl(dsl, j) * di;
            float scB = __shfl(dsl, j + 1) * di;
            float2 vA = ((const float2*)(h + (size_t)sA * 128))[lane];
            float2 vB = ((const float2*)(h + (size_t)sB * 128))[lane];
            ax = fmaf(vA.x, scA, ax); ay = fmaf(vA.y, scA, ay);
            ax = fmaf(vB.x, scB, ax); ay = fmaf(vB.y, scB, ay);
        }
        if (j < m) {
            int sA = __shfl(e, j);
            float scA = __shfl(dsl, j) * di;
            float2 vA = ((const float2*)(h + (size_t)sA * 128))[lane];
            ax = fmaf(vA.x, scA, ax); ay = fmaf(vA.y, scA, ay);
        }
    }
    float2 b = ((const float2*)bias)[lane];
    ax += b.x; ay += b.y;
    if (relu) { ax = fmaxf(ax, 0.f); ay = fmaxf(ay, 0.f); }
    float2 o = {ax, ay};
    ((float2*)(out + (size_t)node * 128))[lane] = o;
}

// ---- aggregation, 40 features: one wave per node, lanes 0..39 ----
__global__ __launch_bounds__(256) void k_agg40(const float* __restrict__ h,
                                               const float* __restrict__ dis,
                                               const int* __restrict__ ptr,
                                               const int* __restrict__ cnt,
                                               const int* __restrict__ esrc,
                                               const float* __restrict__ bias,
                                               float* __restrict__ out, int N) {
    int node = blockIdx.x * 4 + (threadIdx.x >> 6);
    if (node >= N) return;
    int lane = threadIdx.x & 63;
    float di = dis[node];
    float acc = 0.f;
    if (lane < 40) acc = h[(size_t)node * 40 + lane] * di * di;
    int start = ptr[node], c = cnt[node];
    for (int base = 0; base < c; base += 64) {
        int m = min(64, c - base);
        int e = 0;
        float dsl = 0.f;
        if (lane < m) {
            e = esrc[start + base + lane];
            dsl = dis[e];
        }
        for (int j = 0; j < m; ++j) {
            int s = __shfl(e, j);
            float sc = __shfl(dsl, j) * di;
            if (lane < 40) acc = fmaf(h[(size_t)s * 40 + lane], sc, acc);
        }
    }
    if (lane < 40) out[(size_t)node * 40 + lane] = acc + bias[lane];
}

// ---- log_softmax over 40 classes, one wave per row ----
__global__ __launch_bounds__(256) void k_lsm(const float* __restrict__ in,
                                             float* __restrict__ out, int N) {
    int rowi = blockIdx.x * 4 + (threadIdx.x >> 6);
    if (rowi >= N) return;
    int lane = threadIdx.x & 63;
    float v = (lane < 40) ? in[(size_t)rowi * 40 + lane] : -INFINITY;
    float m = v;
#pragma unroll
    for (int o = 32; o; o >>= 1) m = fmaxf(m, __shfl_xor(m, o));
    float ex = (lane < 40) ? expf(v - m) : 0.f;
    float s = ex;
#pragma unroll
    for (int o = 32; o; o >>= 1) s += __shfl_xor(s, o);
    if (lane < 40) out[(size_t)rowi * 40 + lane] = v - m - logf(s);
}

extern "C" void kernel_launch(void* const* d_in, const int* in_sizes, int n_in,
                              void* d_out, int out_size, void* d_ws, size_t ws_size,
                              hipStream_t stream) {
    const float* x  = (const float*)d_in[0];
    const int*   ei = (const int*)d_in[1];
    const float* W1 = (const float*)d_in[2];
    const float* b1 = (const float*)d_in[3];
    const float* W2 = (const float*)d_in[4];
    const float* b2 = (const float*)d_in[5];
    const float* W3 = (const float*)d_in[6];
    const float* b3 = (const float*)d_in[7];
    int N = in_sizes[0] / 128;
    int E = in_sizes[1] / 2;
    const int* row = ei;
    const int* col = ei + E;
    int NB = (N + 255) >> 8;  // buckets of 256 dst nodes (NB <= 512)

    char* ws = (char*)d_ws;
    size_t off = 0;
    auto alloc = [&](size_t bytes) {
        void* p = ws + off;
        off += (bytes + 255) & ~(size_t)255;
        return p;
    };
    float* hA    = (float*)alloc((size_t)N * 128 * 4);
    float* hB    = (float*)alloc((size_t)N * 128 * 4);
    int*   esrc  = (int*)alloc((size_t)E * 4);
    int*   cptr  = (int*)alloc((size_t)N * 4);
    int*   cnt   = (int*)alloc((size_t)N * 4);
    float* dis   = (float*)alloc((size_t)N * 4);
    int*   bsum  = (int*)alloc(256 * 4);
    int*   bhist = (int*)alloc(512 * 4);
    int*   bbase = (int*)alloc(513 * 4);
    int*   bcur  = (int*)alloc(512 * 4);
    // binned staging (E * 8B) aliases hB: hB is first written by agg1,
    // long after k_fill2 has consumed binned.
    uint2* binned = (uint2*)hB;
    float* t3    = hA;                     // reuse hA after agg2 consumed it
    float* t3b   = hA + (size_t)N * 40;

    // ---- CSR build (bucketed) ----
    hipMemsetAsync(bhist, 0, 512 * 4, stream);
    k_bhist<<<512, 256, 0, stream>>>(col, E, NB, bhist);
    k_bscan<<<1, 512, 0, stream>>>(bhist, NB, E, bbase, bcur);
    k_bin<<<(E + 255) / 256, 256, 0, stream>>>(row, col, E, bcur, binned);
    k_cntB<<<NB, 256, 0, stream>>>(binned, bbase, N, cnt);
    int B = (N + 1023) / 1024;  // 98 for N=100000 (must be <=128)
    k_bsum<<<B, 256, 0, stream>>>(cnt, N, bsum);
    k_sbsum<<<1, 128, 0, stream>>>(bsum, B);
    k_wptr<<<B, 256, 0, stream>>>(cnt, bsum, N, cptr, dis);
    k_fill2<<<NB, 256, 0, stream>>>(binned, bbase, cptr, N, esrc);

    // ---- layers ----
    int gb = (N + 63) / 64;
    int ab = (N + 3) / 4;
    k_gemm128<<<gb, 256, 0, stream>>>(x, W1, hA, N);
    k_agg128<<<ab, 256, 0, stream>>>(hA, dis, cptr, cnt, esrc, b1, hB, 1, N);
    k_gemm128<<<gb, 256, 0, stream>>>(hB, W2, hA, N);
    k_agg128<<<ab, 256, 0, stream>>>(hA, dis, cptr, cnt, esrc, b2, hB, 1, N);
    k_gemm40<<<gb, 320, 0, stream>>>(hB, W3, t3, N);
    k_agg40<<<ab, 256, 0, stream>>>(t3, dis, cptr, cnt, esrc, b3, t3b, N);
    k_lsm<<<ab, 256, 0, stream>>>(t3b, (float*)d_out, N);
}

// Round 7
// 701.913 us; speedup vs baseline: 1.7621x; 1.7621x over previous
//
#include <hip/hip_runtime.h>
#include <hip/hip_bf16.h>
#include <math.h>

// ---------------------------------------------------------------------------
// 3-layer GCN: per layer  h' = Dis (A+I) Dis (h W) + b   (Dis = D^{-1/2})
// CSR build = two-level counting sort by 256-node bucket:
//   bhist(global bucket histo) -> bscan ->
//   bin2(LDS histo + bulk reserve + LDS-cursor scatter, packed uint) ->
//   cntB(LDS per-node count) -> scan(ptr,dis) -> fill2(LDS cursors)
// then gemm -> aggregate(+bias,+relu) x3 -> log_softmax
// Bucket = 256 consecutive dst nodes; NB = ceil(N/256) (<=512 assumed).
// binned entry: bits[0,24) = src row, bits[24,32) = dst & 255.
// ---------------------------------------------------------------------------

// ---- bucket histogram: 512-entry LDS histo per block, merged by atomics ----
__global__ __launch_bounds__(256) void k_bhist(const int* __restrict__ col, int E,
                                               int NB, int* __restrict__ bhist) {
    __shared__ int h[512];
    for (int j = threadIdx.x; j < 512; j += 256) h[j] = 0;
    __syncthreads();
    int chunk = (E + gridDim.x - 1) / gridDim.x;
    int lo = blockIdx.x * chunk;
    int hi = min(lo + chunk, E);
    for (int i = lo + threadIdx.x; i < hi; i += 256)
        atomicAdd(&h[col[i] >> 8], 1);
    __syncthreads();
    for (int j = threadIdx.x; j < NB; j += 256) {
        int v = h[j];
        if (v) atomicAdd(&bhist[j], v);
    }
}

// ---- exclusive scan of bucket counts (NB <= 512), one block ----
__global__ __launch_bounds__(512) void k_bscan(const int* __restrict__ bhist,
                                               int NB, int E,
                                               int* __restrict__ bbase,
                                               int* __restrict__ bcur) {
    __shared__ int sm[512];
    int t = threadIdx.x;
    int v = (t < NB) ? bhist[t] : 0;
    sm[t] = v;
    __syncthreads();
    for (int off = 1; off < 512; off <<= 1) {
        int u = (t >= off) ? sm[t - off] : 0;
        __syncthreads();
        sm[t] += u;
        __syncthreads();
    }
    if (t < NB) {
        int ex = sm[t] - v;
        bbase[t] = ex;
        bcur[t] = ex;
    }
    if (t == 0) bbase[NB] = E;
}

// ---- two-level binning: LDS histo -> bulk reserve -> LDS-cursor scatter ----
__global__ __launch_bounds__(256) void k_bin2(const int* __restrict__ row,
                                              const int* __restrict__ col, int E,
                                              int* __restrict__ bcur,
                                              unsigned* __restrict__ binned) {
    __shared__ int h[512];    // per-block bucket histogram, then unused
    __shared__ int base[512]; // per-block bucket cursor
    int t = threadIdx.x;
    for (int j = t; j < 512; j += 256) h[j] = 0;
    __syncthreads();
    int chunk = (E + gridDim.x - 1) / gridDim.x;
    int lo = blockIdx.x * chunk;
    int hi = min(lo + chunk, E);
    for (int i = lo + t; i < hi; i += 256)
        atomicAdd(&h[col[i] >> 8], 1);
    __syncthreads();
    for (int j = t; j < 512; j += 256) {
        int c = h[j];
        base[j] = c ? atomicAdd(&bcur[j], c) : 0;  // reserve contiguous range
    }
    __syncthreads();
    for (int i = lo + t; i < hi; i += 256) {
        int r = row[i], c = col[i];
        int p = atomicAdd(&base[c >> 8], 1);       // LDS cursor
        binned[p] = (unsigned)r | ((unsigned)(c & 255) << 24);
    }
}

// ---- per-node counts from binned data, LDS histogram per bucket ----
__global__ __launch_bounds__(256) void k_cntB(const unsigned* __restrict__ binned,
                                              const int* __restrict__ bbase,
                                              int N, int* __restrict__ cnt) {
    int b = blockIdx.x, t = threadIdx.x;
    __shared__ int sc[256];
    sc[t] = 0;
    __syncthreads();
    int lo = bbase[b], hi = bbase[b + 1];
    for (int i = lo + t; i < hi; i += 256)
        atomicAdd(&sc[binned[i] >> 24], 1);
    __syncthreads();
    int node = b * 256 + t;
    if (node < N) cnt[node] = sc[t];
}

// ---- parallel scan, stage 1: per-block (1024 elems) sums ----
__global__ __launch_bounds__(256) void k_bsum(const int* __restrict__ cnt, int N,
                                              int* __restrict__ bsum) {
    int t = threadIdx.x;
    int base = blockIdx.x * 1024 + t * 4;
    int s = 0;
    if (base + 3 < N) {
        int4 v = *(const int4*)(cnt + base);
        s = v.x + v.y + v.z + v.w;
    } else {
        for (int j = 0; j < 4; ++j)
            if (base + j < N) s += cnt[base + j];
    }
#pragma unroll
    for (int off = 32; off; off >>= 1) s += __shfl_xor(s, off);
    __shared__ int ws[4];
    int lane = t & 63, w = t >> 6;
    if (lane == 0) ws[w] = s;
    __syncthreads();
    if (t == 0) bsum[blockIdx.x] = ws[0] + ws[1] + ws[2] + ws[3];
}

// ---- stage 2: exclusive scan of block sums (B <= 128), one tiny block ----
__global__ __launch_bounds__(128) void k_sbsum(int* __restrict__ bsum, int B) {
    __shared__ int sm[128];
    int t = threadIdx.x;
    int v = (t < B) ? bsum[t] : 0;
    sm[t] = v;
    __syncthreads();
    for (int off = 1; off < 128; off <<= 1) {
        int u = (t >= off) ? sm[t - off] : 0;
        __syncthreads();
        sm[t] += u;
        __syncthreads();
    }
    if (t < B) bsum[t] = sm[t] - v;  // exclusive prefix
}

// ---- stage 3: per-block exclusive scan + write ptr/dis ----
__global__ __launch_bounds__(256) void k_wptr(const int* __restrict__ cnt,
                                              const int* __restrict__ bsum, int N,
                                              int* __restrict__ ptr,
                                              float* __restrict__ dis) {
    int t = threadIdx.x;
    int base = blockIdx.x * 1024 + t * 4;
    int c[4];
    int s = 0;
    if (base + 3 < N) {
        int4 v = *(const int4*)(cnt + base);
        c[0] = v.x; c[1] = v.y; c[2] = v.z; c[3] = v.w;
        s = v.x + v.y + v.z + v.w;
    } else {
#pragma unroll
        for (int j = 0; j < 4; ++j) {
            c[j] = (base + j < N) ? cnt[base + j] : 0;
            s += c[j];
        }
    }
    int lane = t & 63, w = t >> 6;
    int incl = s;
#pragma unroll
    for (int off = 1; off < 64; off <<= 1) {
        int u = __shfl_up(incl, off);
        if (lane >= off) incl += u;
    }
    __shared__ int wsum[4];
    if (lane == 63) wsum[w] = incl;
    __syncthreads();
    int run = bsum[blockIdx.x] + (incl - s);
    for (int j = 0; j < w; ++j) run += wsum[j];
#pragma unroll
    for (int j = 0; j < 4; ++j) {
        int i = base + j;
        if (i < N) {
            ptr[i] = run;
            dis[i] = rsqrtf((float)(c[j] + 1));  // +1 self-loop
            run += c[j];
        }
    }
}

// ---- CSR fill from binned data with LDS cursors (L2-local esrc writes) ----
__global__ __launch_bounds__(256) void k_fill2(const unsigned* __restrict__ binned,
                                               const int* __restrict__ bbase,
                                               const int* __restrict__ ptr, int N,
                                               int* __restrict__ esrc) {
    int b = blockIdx.x, t = threadIdx.x;
    __shared__ int lc[256];
    int node = b * 256 + t;
    lc[t] = (node < N) ? ptr[node] : 0;
    __syncthreads();
    int lo = bbase[b], hi = bbase[b + 1];
    for (int i = lo + t; i < hi; i += 256) {
        unsigned e = binned[i];
        int p = atomicAdd(&lc[e >> 24], 1);
        esrc[p] = (int)(e & 0xFFFFFFu);
    }
}

// ---- GEMM: Y[M][128] = X[M][128] @ W[128][128], no bias (added post-agg) ----
__global__ __launch_bounds__(256) void k_gemm128(const float* __restrict__ X,
                                                 const float* __restrict__ W,
                                                 float* __restrict__ Y, int M) {
    __shared__ float wsm[64 * 128];  // 32 KB: W rows [kp*64, kp*64+64)
    __shared__ float xs[64 * 68];    // 17 KB: X tile [64 rows][64 k], pad 68
    int t = threadIdx.x;
    int row0 = blockIdx.x * 64;
    int cg = t & 15, rg = t >> 4;
    float acc[4][8];
#pragma unroll
    for (int a = 0; a < 4; ++a)
#pragma unroll
        for (int b = 0; b < 8; ++b) acc[a][b] = 0.f;

    for (int kp = 0; kp < 2; ++kp) {
        const float4* W4 = (const float4*)W;
        float4* wd = (float4*)wsm;
#pragma unroll
        for (int i = 0; i < 8; ++i) {
            int idx = t + i * 256;
            wd[idx] = W4[kp * 2048 + idx];
        }
        const float4* X4 = (const float4*)X;
#pragma unroll
        for (int i = 0; i < 4; ++i) {
            int idx = t + i * 256;
            int r = idx >> 4, c4 = idx & 15;
            float4 v = {0.f, 0.f, 0.f, 0.f};
            if (row0 + r < M) v = X4[(size_t)(row0 + r) * 32 + kp * 16 + c4];
            float* dst = &xs[r * 68 + c4 * 4];
            dst[0] = v.x; dst[1] = v.y; dst[2] = v.z; dst[3] = v.w;
        }
        __syncthreads();
#pragma unroll 4
        for (int k = 0; k < 64; ++k) {
            float a0 = xs[(rg * 4 + 0) * 68 + k];
            float a1 = xs[(rg * 4 + 1) * 68 + k];
            float a2 = xs[(rg * 4 + 2) * 68 + k];
            float a3 = xs[(rg * 4 + 3) * 68 + k];
            const float* wr = &wsm[k * 128 + cg * 8];
            float4 w0 = *(const float4*)wr;
            float4 w1 = *(const float4*)(wr + 4);
            float wv[8] = {w0.x, w0.y, w0.z, w0.w, w1.x, w1.y, w1.z, w1.w};
#pragma unroll
            for (int b = 0; b < 8; ++b) {
                acc[0][b] = fmaf(a0, wv[b], acc[0][b]);
                acc[1][b] = fmaf(a1, wv[b], acc[1][b]);
                acc[2][b] = fmaf(a2, wv[b], acc[2][b]);
                acc[3][b] = fmaf(a3, wv[b], acc[3][b]);
            }
        }
        __syncthreads();
    }
#pragma unroll
    for (int a = 0; a < 4; ++a) {
        int r = row0 + rg * 4 + a;
        if (r < M) {
            float4* dst = (float4*)&Y[(size_t)r * 128 + cg * 8];
            float4 o0 = {acc[a][0], acc[a][1], acc[a][2], acc[a][3]};
            float4 o1 = {acc[a][4], acc[a][5], acc[a][6], acc[a][7]};
            dst[0] = o0;
            dst[1] = o1;
        }
    }
}

// ---- GEMM: Y[M][40] = X[M][128] @ W[128][40] ----
__global__ __launch_bounds__(320) void k_gemm40(const float* __restrict__ X,
                                                const float* __restrict__ W,
                                                float* __restrict__ Y, int M) {
    __shared__ float wsm[128 * 40];  // 20 KB
    __shared__ float xs[64 * 133];   // 34 KB
    int t = threadIdx.x;
    int row0 = blockIdx.x * 64;
    for (int idx = t; idx < 128 * 40; idx += 320) wsm[idx] = W[idx];
    for (int idx = t; idx < 64 * 128; idx += 320) {
        int r = idx >> 7, c = idx & 127;
        xs[r * 133 + c] = (row0 + r < M) ? X[(size_t)(row0 + r) * 128 + c] : 0.f;
    }
    __syncthreads();
    int lane = t & 63, cg = t >> 6;  // cg 0..4
    float acc[8];
#pragma unroll
    for (int b = 0; b < 8; ++b) acc[b] = 0.f;
#pragma unroll 4
    for (int k = 0; k < 128; ++k) {
        float a = xs[lane * 133 + k];
        const float* wr = &wsm[k * 40 + cg * 8];
        float4 w0 = *(const float4*)wr;
        float4 w1 = *(const float4*)(wr + 4);
        acc[0] = fmaf(a, w0.x, acc[0]); acc[1] = fmaf(a, w0.y, acc[1]);
        acc[2] = fmaf(a, w0.z, acc[2]); acc[3] = fmaf(a, w0.w, acc[3]);
        acc[4] = fmaf(a, w1.x, acc[4]); acc[5] = fmaf(a, w1.y, acc[5]);
        acc[6] = fmaf(a, w1.z, acc[6]); acc[7] = fmaf(a, w1.w, acc[7]);
    }
    int r = row0 + lane;
    if (r < M) {
        float4* dst = (float4*)&Y[(size_t)r * 40 + cg * 8];
        float4 o0 = {acc[0], acc[1], acc[2], acc[3]};
        float4 o1 = {acc[4], acc[5], acc[6], acc[7]};
        dst[0] = o0;
        dst[1] = o1;
    }
}

// ---- aggregation, 128 features: one wave per node, lane owns float2 ----
__global__ __launch_bounds__(256) void k_agg128(const float* __restrict__ h,
                                                const float* __restrict__ dis,
                                                const int* __restrict__ ptr,
                                                const int* __restrict__ cnt,
                                                const int* __restrict__ esrc,
                                                const float* __restrict__ bias,
                                                float* __restrict__ out,
                                                int relu, int N) {
    int node = blockIdx.x * 4 + (threadIdx.x >> 6);
    if (node >= N) return;
    int lane = threadIdx.x & 63;
    float di = dis[node];
    const float2* hrow = (const float2*)(h + (size_t)node * 128);
    float2 self = hrow[lane];
    float w = di * di;
    float ax = self.x * w, ay = self.y * w;
    int start = ptr[node], c = cnt[node];
    for (int base = 0; base < c; base += 64) {
        int m = min(64, c - base);
        int e = 0;
        float dsl = 0.f;
        if (lane < m) {
            e = esrc[start + base + lane];
            dsl = dis[e];
        }
        int j = 0;
        for (; j + 2 <= m; j += 2) {
            int sA = __shfl(e, j), sB = __shfl(e, j + 1);
            float scA = __shfl(dsl, j) * di;
            float scB = __shfl(dsl, j + 1) * di;
            float2 vA = ((const float2*)(h + (size_t)sA * 128))[lane];
            float2 vB = ((const float2*)(h + (size_t)sB * 128))[lane];
            ax = fmaf(vA.x, scA, ax); ay = fmaf(vA.y, scA, ay);
            ax = fmaf(vB.x, scB, ax); ay = fmaf(vB.y, scB, ay);
        }
        if (j < m) {
            int sA = __shfl(e, j);
            float scA = __shfl(dsl, j) * di;
            float2 vA = ((const float2*)(h + (size_t)sA * 128))[lane];
            ax = fmaf(vA.x, scA, ax); ay = fmaf(vA.y, scA, ay);
        }
    }
    float2 b = ((const float2*)bias)[lane];
    ax += b.x; ay += b.y;
    if (relu) { ax = fmaxf(ax, 0.f); ay = fmaxf(ay, 0.f); }
    float2 o = {ax, ay};
    ((float2*)(out + (size_t)node * 128))[lane] = o;
}

// ---- aggregation, 40 features: one wave per node, lanes 0..39 ----
__global__ __launch_bounds__(256) void k_agg40(const float* __restrict__ h,
                                               const float* __restrict__ dis,
                                               const int* __restrict__ ptr,
                                               const int* __restrict__ cnt,
                                               const int* __restrict__ esrc,
                                               const float* __restrict__ bias,
                                               float* __restrict__ out, int N) {
    int node = blockIdx.x * 4 + (threadIdx.x >> 6);
    if (node >= N) return;
    int lane = threadIdx.x & 63;
    float di = dis[node];
    float acc = 0.f;
    if (lane < 40) acc = h[(size_t)node * 40 + lane] * di * di;
    int start = ptr[node], c = cnt[node];
    for (int base = 0; base < c; base += 64) {
        int m = min(64, c - base);
        int e = 0;
        float dsl = 0.f;
        if (lane < m) {
            e = esrc[start + base + lane];
            dsl = dis[e];
        }
        for (int j = 0; j < m; ++j) {
            int s = __shfl(e, j);
            float sc = __shfl(dsl, j) * di;
            if (lane < 40) acc = fmaf(h[(size_t)s * 40 + lane], sc, acc);
        }
    }
    if (lane < 40) out[(size_t)node * 40 + lane] = acc + bias[lane];
}

// ---- log_softmax over 40 classes, one wave per row ----
__global__ __launch_bounds__(256) void k_lsm(const float* __restrict__ in,
                                             float* __restrict__ out, int N) {
    int rowi = blockIdx.x * 4 + (threadIdx.x >> 6);
    if (rowi >= N) return;
    int lane = threadIdx.x & 63;
    float v = (lane < 40) ? in[(size_t)rowi * 40 + lane] : -INFINITY;
    float m = v;
#pragma unroll
    for (int o = 32; o; o >>= 1) m = fmaxf(m, __shfl_xor(m, o));
    float ex = (lane < 40) ? expf(v - m) : 0.f;
    float s = ex;
#pragma unroll
    for (int o = 32; o; o >>= 1) s += __shfl_xor(s, o);
    if (lane < 40) out[(size_t)rowi * 40 + lane] = v - m - logf(s);
}

extern "C" void kernel_launch(void* const* d_in, const int* in_sizes, int n_in,
                              void* d_out, int out_size, void* d_ws, size_t ws_size,
                              hipStream_t stream) {
    const float* x  = (const float*)d_in[0];
    const int*   ei = (const int*)d_in[1];
    const float* W1 = (const float*)d_in[2];
    const float* b1 = (const float*)d_in[3];
    const float* W2 = (const float*)d_in[4];
    const float* b2 = (const float*)d_in[5];
    const float* W3 = (const float*)d_in[6];
    const float* b3 = (const float*)d_in[7];
    int N = in_sizes[0] / 128;
    int E = in_sizes[1] / 2;
    const int* row = ei;
    const int* col = ei + E;
    int NB = (N + 255) >> 8;  // buckets of 256 dst nodes (NB <= 512)

    char* ws = (char*)d_ws;
    size_t off = 0;
    auto alloc = [&](size_t bytes) {
        void* p = ws + off;
        off += (bytes + 255) & ~(size_t)255;
        return p;
    };
    float* hA    = (float*)alloc((size_t)N * 128 * 4);
    float* hB    = (float*)alloc((size_t)N * 128 * 4);
    int*   esrc  = (int*)alloc((size_t)E * 4);
    int*   cptr  = (int*)alloc((size_t)N * 4);
    int*   cnt   = (int*)alloc((size_t)N * 4);
    float* dis   = (float*)alloc((size_t)N * 4);
    int*   bsum  = (int*)alloc(256 * 4);
    int*   bhist = (int*)alloc(512 * 4);
    int*   bbase = (int*)alloc(513 * 4);
    int*   bcur  = (int*)alloc(512 * 4);
    // binned staging (E * 4B packed) aliases hB: hB is first written by agg1,
    // long after k_fill2 has consumed binned.
    unsigned* binned = (unsigned*)hB;
    float* t3    = hA;                     // reuse hA after agg2 consumed it
    float* t3b   = hA + (size_t)N * 40;

    // ---- CSR build (two-level counting sort) ----
    hipMemsetAsync(bhist, 0, 512 * 4, stream);
    k_bhist<<<256, 256, 0, stream>>>(col, E, NB, bhist);
    k_bscan<<<1, 512, 0, stream>>>(bhist, NB, E, bbase, bcur);
    k_bin2<<<256, 256, 0, stream>>>(row, col, E, bcur, binned);
    k_cntB<<<NB, 256, 0, stream>>>(binned, bbase, N, cnt);
    int B = (N + 1023) / 1024;  // 98 for N=100000 (must be <=128)
    k_bsum<<<B, 256, 0, stream>>>(cnt, N, bsum);
    k_sbsum<<<1, 128, 0, stream>>>(bsum, B);
    k_wptr<<<B, 256, 0, stream>>>(cnt, bsum, N, cptr, dis);
    k_fill2<<<NB, 256, 0, stream>>>(binned, bbase, cptr, N, esrc);

    // ---- layers ----
    int gb = (N + 63) / 64;
    int ab = (N + 3) / 4;
    k_gemm128<<<gb, 256, 0, stream>>>(x, W1, hA, N);
    k_agg128<<<ab, 256, 0, stream>>>(hA, dis, cptr, cnt, esrc, b1, hB, 1, N);
    k_gemm128<<<gb, 256, 0, stream>>>(hB, W2, hA, N);
    k_agg128<<<ab, 256, 0, stream>>>(hA, dis, cptr, cnt, esrc, b2, hB, 1, N);
    k_gemm40<<<gb, 320, 0, stream>>>(hB, W3, t3, N);
    k_agg40<<<ab, 256, 0, stream>>>(t3, dis, cptr, cnt, esrc, b3, t3b, N);
    k_lsm<<<ab, 256, 0, stream>>>(t3b, (float*)d_out, N);
}

// Round 9
// 577.503 us; speedup vs baseline: 2.1417x; 1.2154x over previous
//
#include <hip/hip_runtime.h>
#include <hip/hip_bf16.h>
#include <math.h>

// ---------------------------------------------------------------------------
// 3-layer GCN, bf16 hidden activations (f32 accumulation everywhere).
// CSR build = two-level counting sort by 256-node bucket (round-7 pipeline).
// gemm1(f32 in -> bf16 out) -> agg128(bf16) -> gemm2(bf16 -> bf16) ->
// agg128(bf16) -> gemm40(bf16 -> f32) -> agg40(f32) -> log_softmax(f32)
// ---------------------------------------------------------------------------

__device__ inline float bfu(unsigned short s) {
    return __uint_as_float((unsigned)s << 16);
}
__device__ inline float bf16lo(unsigned u) { return __uint_as_float(u << 16); }
__device__ inline float bf16hi(unsigned u) { return __uint_as_float(u & 0xFFFF0000u); }
__device__ inline unsigned packbf2(float a, float b) {
    __hip_bfloat16 x = __float2bfloat16(a), y = __float2bfloat16(b);
    unsigned short ux = *(unsigned short*)&x, uy = *(unsigned short*)&y;
    return (unsigned)ux | ((unsigned)uy << 16);
}
__device__ inline unsigned short bf1(float a) {
    __hip_bfloat16 x = __float2bfloat16(a);
    return *(unsigned short*)&x;
}

// ---- bucket histogram ----
__global__ __launch_bounds__(256) void k_bhist(const int* __restrict__ col, int E,
                                               int NB, int* __restrict__ bhist) {
    __shared__ int h[512];
    for (int j = threadIdx.x; j < 512; j += 256) h[j] = 0;
    __syncthreads();
    int chunk = (E + gridDim.x - 1) / gridDim.x;
    int lo = blockIdx.x * chunk;
    int hi = min(lo + chunk, E);
    for (int i = lo + threadIdx.x; i < hi; i += 256)
        atomicAdd(&h[col[i] >> 8], 1);
    __syncthreads();
    for (int j = threadIdx.x; j < NB; j += 256) {
        int v = h[j];
        if (v) atomicAdd(&bhist[j], v);
    }
}

// ---- exclusive scan of bucket counts ----
__global__ __launch_bounds__(512) void k_bscan(const int* __restrict__ bhist,
                                               int NB, int E,
                                               int* __restrict__ bbase,
                                               int* __restrict__ bcur) {
    __shared__ int sm[512];
    int t = threadIdx.x;
    int v = (t < NB) ? bhist[t] : 0;
    sm[t] = v;
    __syncthreads();
    for (int off = 1; off < 512; off <<= 1) {
        int u = (t >= off) ? sm[t - off] : 0;
        __syncthreads();
        sm[t] += u;
        __syncthreads();
    }
    if (t < NB) {
        int ex = sm[t] - v;
        bbase[t] = ex;
        bcur[t] = ex;
    }
    if (t == 0) bbase[NB] = E;
}

// ---- two-level binning ----
__global__ __launch_bounds__(256) void k_bin2(const int* __restrict__ row,
                                              const int* __restrict__ col, int E,
                                              int* __restrict__ bcur,
                                              unsigned* __restrict__ binned) {
    __shared__ int h[512];
    __shared__ int base[512];
    int t = threadIdx.x;
    for (int j = t; j < 512; j += 256) h[j] = 0;
    __syncthreads();
    int chunk = (E + gridDim.x - 1) / gridDim.x;
    int lo = blockIdx.x * chunk;
    int hi = min(lo + chunk, E);
    for (int i = lo + t; i < hi; i += 256)
        atomicAdd(&h[col[i] >> 8], 1);
    __syncthreads();
    for (int j = t; j < 512; j += 256) {
        int c = h[j];
        base[j] = c ? atomicAdd(&bcur[j], c) : 0;
    }
    __syncthreads();
    for (int i = lo + t; i < hi; i += 256) {
        int r = row[i], c = col[i];
        int p = atomicAdd(&base[c >> 8], 1);
        binned[p] = (unsigned)r | ((unsigned)(c & 255) << 24);
    }
}

// ---- per-node counts ----
__global__ __launch_bounds__(256) void k_cntB(const unsigned* __restrict__ binned,
                                              const int* __restrict__ bbase,
                                              int N, int* __restrict__ cnt) {
    int b = blockIdx.x, t = threadIdx.x;
    __shared__ int sc[256];
    sc[t] = 0;
    __syncthreads();
    int lo = bbase[b], hi = bbase[b + 1];
    for (int i = lo + t; i < hi; i += 256)
        atomicAdd(&sc[binned[i] >> 24], 1);
    __syncthreads();
    int node = b * 256 + t;
    if (node < N) cnt[node] = sc[t];
}

// ---- scan stage 1 ----
__global__ __launch_bounds__(256) void k_bsum(const int* __restrict__ cnt, int N,
                                              int* __restrict__ bsum) {
    int t = threadIdx.x;
    int base = blockIdx.x * 1024 + t * 4;
    int s = 0;
    if (base + 3 < N) {
        int4 v = *(const int4*)(cnt + base);
        s = v.x + v.y + v.z + v.w;
    } else {
        for (int j = 0; j < 4; ++j)
            if (base + j < N) s += cnt[base + j];
    }
#pragma unroll
    for (int off = 32; off; off >>= 1) s += __shfl_xor(s, off);
    __shared__ int ws[4];
    int lane = t & 63, w = t >> 6;
    if (lane == 0) ws[w] = s;
    __syncthreads();
    if (t == 0) bsum[blockIdx.x] = ws[0] + ws[1] + ws[2] + ws[3];
}

// ---- scan stage 2 ----
__global__ __launch_bounds__(128) void k_sbsum(int* __restrict__ bsum, int B) {
    __shared__ int sm[128];
    int t = threadIdx.x;
    int v = (t < B) ? bsum[t] : 0;
    sm[t] = v;
    __syncthreads();
    for (int off = 1; off < 128; off <<= 1) {
        int u = (t >= off) ? sm[t - off] : 0;
        __syncthreads();
        sm[t] += u;
        __syncthreads();
    }
    if (t < B) bsum[t] = sm[t] - v;
}

// ---- scan stage 3: ptr/dis ----
__global__ __launch_bounds__(256) void k_wptr(const int* __restrict__ cnt,
                                              const int* __restrict__ bsum, int N,
                                              int* __restrict__ ptr,
                                              float* __restrict__ dis) {
    int t = threadIdx.x;
    int base = blockIdx.x * 1024 + t * 4;
    int c[4];
    int s = 0;
    if (base + 3 < N) {
        int4 v = *(const int4*)(cnt + base);
        c[0] = v.x; c[1] = v.y; c[2] = v.z; c[3] = v.w;
        s = v.x + v.y + v.z + v.w;
    } else {
#pragma unroll
        for (int j = 0; j < 4; ++j) {
            c[j] = (base + j < N) ? cnt[base + j] : 0;
            s += c[j];
        }
    }
    int lane = t & 63, w = t >> 6;
    int incl = s;
#pragma unroll
    for (int off = 1; off < 64; off <<= 1) {
        int u = __shfl_up(incl, off);
        if (lane >= off) incl += u;
    }
    __shared__ int wsum[4];
    if (lane == 63) wsum[w] = incl;
    __syncthreads();
    int run = bsum[blockIdx.x] + (incl - s);
    for (int j = 0; j < w; ++j) run += wsum[j];
#pragma unroll
    for (int j = 0; j < 4; ++j) {
        int i = base + j;
        if (i < N) {
            ptr[i] = run;
            dis[i] = rsqrtf((float)(c[j] + 1));
            run += c[j];
        }
    }
}

// ---- CSR fill ----
__global__ __launch_bounds__(256) void k_fill2(const unsigned* __restrict__ binned,
                                               const int* __restrict__ bbase,
                                               const int* __restrict__ ptr, int N,
                                               int* __restrict__ esrc) {
    int b = blockIdx.x, t = threadIdx.x;
    __shared__ int lc[256];
    int node = b * 256 + t;
    lc[t] = (node < N) ? ptr[node] : 0;
    __syncthreads();
    int lo = bbase[b], hi = bbase[b + 1];
    for (int i = lo + t; i < hi; i += 256) {
        unsigned e = binned[i];
        int p = atomicAdd(&lc[e >> 24], 1);
        esrc[p] = (int)(e & 0xFFFFFFu);
    }
}

// ---- GEMM layer1: X f32 [M][128] @ W f32 -> Y bf16 [M][128] ----
__global__ __launch_bounds__(256) void k_gemm128_f32(const float* __restrict__ X,
                                                     const float* __restrict__ W,
                                                     unsigned short* __restrict__ Y,
                                                     int M) {
    __shared__ float wsm[64 * 128];
    __shared__ float xs[64 * 68];
    int t = threadIdx.x;
    int row0 = blockIdx.x * 64;
    int cg = t & 15, rg = t >> 4;
    float acc[4][8];
#pragma unroll
    for (int a = 0; a < 4; ++a)
#pragma unroll
        for (int b = 0; b < 8; ++b) acc[a][b] = 0.f;

    for (int kp = 0; kp < 2; ++kp) {
        const float4* W4 = (const float4*)W;
        float4* wd = (float4*)wsm;
#pragma unroll
        for (int i = 0; i < 8; ++i) {
            int idx = t + i * 256;
            wd[idx] = W4[kp * 2048 + idx];
        }
        const float4* X4 = (const float4*)X;
#pragma unroll
        for (int i = 0; i < 4; ++i) {
            int idx = t + i * 256;
            int r = idx >> 4, c4 = idx & 15;
            float4 v = {0.f, 0.f, 0.f, 0.f};
            if (row0 + r < M) v = X4[(size_t)(row0 + r) * 32 + kp * 16 + c4];
            float* dst = &xs[r * 68 + c4 * 4];
            dst[0] = v.x; dst[1] = v.y; dst[2] = v.z; dst[3] = v.w;
        }
        __syncthreads();
#pragma unroll 4
        for (int k = 0; k < 64; ++k) {
            float a0 = xs[(rg * 4 + 0) * 68 + k];
            float a1 = xs[(rg * 4 + 1) * 68 + k];
            float a2 = xs[(rg * 4 + 2) * 68 + k];
            float a3 = xs[(rg * 4 + 3) * 68 + k];
            const float* wr = &wsm[k * 128 + cg * 8];
            float4 w0 = *(const float4*)wr;
            float4 w1 = *(const float4*)(wr + 4);
            float wv[8] = {w0.x, w0.y, w0.z, w0.w, w1.x, w1.y, w1.z, w1.w};
#pragma unroll
            for (int b = 0; b < 8; ++b) {
                acc[0][b] = fmaf(a0, wv[b], acc[0][b]);
                acc[1][b] = fmaf(a1, wv[b], acc[1][b]);
                acc[2][b] = fmaf(a2, wv[b], acc[2][b]);
                acc[3][b] = fmaf(a3, wv[b], acc[3][b]);
            }
        }
        __syncthreads();
    }
#pragma unroll
    for (int a = 0; a < 4; ++a) {
        int r = row0 + rg * 4 + a;
        if (r < M) {
            uint4 o;
            o.x = packbf2(acc[a][0], acc[a][1]);
            o.y = packbf2(acc[a][2], acc[a][3]);
            o.z = packbf2(acc[a][4], acc[a][5]);
            o.w = packbf2(acc[a][6], acc[a][7]);
            *(uint4*)&Y[(size_t)r * 128 + cg * 8] = o;
        }
    }
}

// ---- GEMM layer2: X bf16 [M][128] @ W f32 -> Y bf16 [M][128] ----
__global__ __launch_bounds__(256) void k_gemm128_bf16(const unsigned short* __restrict__ X,
                                                      const float* __restrict__ W,
                                                      unsigned short* __restrict__ Y,
                                                      int M) {
    __shared__ float wsm[64 * 128];
    __shared__ float xs[64 * 68];
    int t = threadIdx.x;
    int row0 = blockIdx.x * 64;
    int cg = t & 15, rg = t >> 4;
    float acc[4][8];
#pragma unroll
    for (int a = 0; a < 4; ++a)
#pragma unroll
        for (int b = 0; b < 8; ++b) acc[a][b] = 0.f;

    for (int kp = 0; kp < 2; ++kp) {
        const float4* W4 = (const float4*)W;
        float4* wd = (float4*)wsm;
#pragma unroll
        for (int i = 0; i < 8; ++i) {
            int idx = t + i * 256;
            wd[idx] = W4[kp * 2048 + idx];
        }
        const ushort4* X4 = (const ushort4*)X;
#pragma unroll
        for (int i = 0; i < 4; ++i) {
            int idx = t + i * 256;
            int r = idx >> 4, c4 = idx & 15;
            float v0 = 0.f, v1 = 0.f, v2 = 0.f, v3 = 0.f;
            if (row0 + r < M) {
                ushort4 v = X4[(size_t)(row0 + r) * 32 + kp * 16 + c4];
                v0 = bfu(v.x); v1 = bfu(v.y); v2 = bfu(v.z); v3 = bfu(v.w);
            }
            float* dst = &xs[r * 68 + c4 * 4];
            dst[0] = v0; dst[1] = v1; dst[2] = v2; dst[3] = v3;
        }
        __syncthreads();
#pragma unroll 4
        for (int k = 0; k < 64; ++k) {
            float a0 = xs[(rg * 4 + 0) * 68 + k];
            float a1 = xs[(rg * 4 + 1) * 68 + k];
            float a2 = xs[(rg * 4 + 2) * 68 + k];
            float a3 = xs[(rg * 4 + 3) * 68 + k];
            const float* wr = &wsm[k * 128 + cg * 8];
            float4 w0 = *(const float4*)wr;
            float4 w1 = *(const float4*)(wr + 4);
            float wv[8] = {w0.x, w0.y, w0.z, w0.w, w1.x, w1.y, w1.z, w1.w};
#pragma unroll
            for (int b = 0; b < 8; ++b) {
                acc[0][b] = fmaf(a0, wv[b], acc[0][b]);
                acc[1][b] = fmaf(a1, wv[b], acc[1][b]);
                acc[2][b] = fmaf(a2, wv[b], acc[2][b]);
                acc[3][b] = fmaf(a3, wv[b], acc[3][b]);
            }
        }
        __syncthreads();
    }
#pragma unroll
    for (int a = 0; a < 4; ++a) {
        int r = row0 + rg * 4 + a;
        if (r < M) {
            uint4 o;
            o.x = packbf2(acc[a][0], acc[a][1]);
            o.y = packbf2(acc[a][2], acc[a][3]);
            o.z = packbf2(acc[a][4], acc[a][5]);
            o.w = packbf2(acc[a][6], acc[a][7]);
            *(uint4*)&Y[(size_t)r * 128 + cg * 8] = o;
        }
    }
}

// ---- GEMM layer3: X bf16 [M][128] @ W f32 [128][40] -> Y f32 [M][40] ----
__global__ __launch_bounds__(320) void k_gemm40(const unsigned short* __restrict__ X,
                                                const float* __restrict__ W,
                                                float* __restrict__ Y, int M) {
    __shared__ float wsm[128 * 40];
    __shared__ float xs[64 * 133];
    int t = threadIdx.x;
    int row0 = blockIdx.x * 64;
    for (int idx = t; idx < 128 * 40; idx += 320) wsm[idx] = W[idx];
    const ushort4* X4 = (const ushort4*)X;
    for (int idx = t; idx < 2048; idx += 320) {
        int r = idx >> 5, c4 = idx & 31;
        float v0 = 0.f, v1 = 0.f, v2 = 0.f, v3 = 0.f;
        if (row0 + r < M) {
            ushort4 v = X4[(size_t)(row0 + r) * 32 + c4];
            v0 = bfu(v.x); v1 = bfu(v.y); v2 = bfu(v.z); v3 = bfu(v.w);
        }
        float* dst = &xs[r * 133 + c4 * 4];
        dst[0] = v0; dst[1] = v1; dst[2] = v2; dst[3] = v3;
    }
    __syncthreads();
    int lane = t & 63, cg = t >> 6;
    float acc[8];
#pragma unroll
    for (int b = 0; b < 8; ++b) acc[b] = 0.f;
#pragma unroll 4
    for (int k = 0; k < 128; ++k) {
        float a = xs[lane * 133 + k];
        const float* wr = &wsm[k * 40 + cg * 8];
        float4 w0 = *(const float4*)wr;
        float4 w1 = *(const float4*)(wr + 4);
        acc[0] = fmaf(a, w0.x, acc[0]); acc[1] = fmaf(a, w0.y, acc[1]);
        acc[2] = fmaf(a, w0.z, acc[2]); acc[3] = fmaf(a, w0.w, acc[3]);
        acc[4] = fmaf(a, w1.x, acc[4]); acc[5] = fmaf(a, w1.y, acc[5]);
        acc[6] = fmaf(a, w1.z, acc[6]); acc[7] = fmaf(a, w1.w, acc[7]);
    }
    int r = row0 + lane;
    if (r < M) {
        float4* dst = (float4*)&Y[(size_t)r * 40 + cg * 8];
        float4 o0 = {acc[0], acc[1], acc[2], acc[3]};
        float4 o1 = {acc[4], acc[5], acc[6], acc[7]};
        dst[0] = o0;
        dst[1] = o1;
    }
}

// ---- aggregation, 128 bf16 features: one wave per node, lane owns 2 ----
__global__ __launch_bounds__(256) void k_agg128(const unsigned short* __restrict__ h,
                                                const float* __restrict__ dis,
                                                const int* __restrict__ ptr,
                                                const int* __restrict__ cnt,
                                                const int* __restrict__ esrc,
                                                const float* __restrict__ bias,
                                                unsigned short* __restrict__ out,
                                                int relu, int N) {
    int node = blockIdx.x * 4 + (threadIdx.x >> 6);
    if (node >= N) return;
    int lane = threadIdx.x & 63;
    float di = dis[node];
    const unsigned* h32 = (const unsigned*)h;
    unsigned su = h32[(size_t)node * 64 + lane];
    float w = di * di;
    float ax = bf16lo(su) * w, ay = bf16hi(su) * w;
    int start = ptr[node], c = cnt[node];
    for (int base = 0; base < c; base += 64) {
        int m = min(64, c - base);
        int e = 0;
        float dsl = 0.f;
        if (lane < m) {
            e = esrc[start + base + lane];
            dsl = dis[e];
        }
        int j = 0;
        for (; j + 2 <= m; j += 2) {
            int sA = __shfl(e, j), sB = __shfl(e, j + 1);
            float scA = __shfl(dsl, j) * di;
            float scB = __shfl(dsl, j + 1) * di;
            unsigned uA = h32[(size_t)sA * 64 + lane];
            unsigned uB = h32[(size_t)sB * 64 + lane];
            ax = fmaf(bf16lo(uA), scA, ax); ay = fmaf(bf16hi(uA), scA, ay);
            ax = fmaf(bf16lo(uB), scB, ax); ay = fmaf(bf16hi(uB), scB, ay);
        }
        if (j < m) {
            int sA = __shfl(e, j);
            float scA = __shfl(dsl, j) * di;
            unsigned uA = h32[(size_t)sA * 64 + lane];
            ax = fmaf(bf16lo(uA), scA, ax); ay = fmaf(bf16hi(uA), scA, ay);
        }
    }
    float2 b = ((const float2*)bias)[lane];
    ax += b.x; ay += b.y;
    if (relu) { ax = fmaxf(ax, 0.f); ay = fmaxf(ay, 0.f); }
    ((unsigned*)out)[(size_t)node * 64 + lane] = packbf2(ax, ay);
}

// ---- aggregation, 40 f32 features ----
__global__ __launch_bounds__(256) void k_agg40(const float* __restrict__ h,
                                               const float* __restrict__ dis,
                                               const int* __restrict__ ptr,
                                               const int* __restrict__ cnt,
                                               const int* __restrict__ esrc,
                                               const float* __restrict__ bias,
                                               float* __restrict__ out, int N) {
    int node = blockIdx.x * 4 + (threadIdx.x >> 6);
    if (node >= N) return;
    int lane = threadIdx.x & 63;
    float di = dis[node];
    float acc = 0.f;
    if (lane < 40) acc = h[(size_t)node * 40 + lane] * di * di;
    int start = ptr[node], c = cnt[node];
    for (int base = 0; base < c; base += 64) {
        int m = min(64, c - base);
        int e = 0;
        float dsl = 0.f;
        if (lane < m) {
            e = esrc[start + base + lane];
            dsl = dis[e];
        }
        for (int j = 0; j < m; ++j) {
            int s = __shfl(e, j);
            float sc = __shfl(dsl, j) * di;
            if (lane < 40) acc = fmaf(h[(size_t)s * 40 + lane], sc, acc);
        }
    }
    if (lane < 40) out[(size_t)node * 40 + lane] = acc + bias[lane];
}

// ---- log_softmax over 40 classes ----
__global__ __launch_bounds__(256) void k_lsm(const float* __restrict__ in,
                                             float* __restrict__ out, int N) {
    int rowi = blockIdx.x * 4 + (threadIdx.x >> 6);
    if (rowi >= N) return;
    int lane = threadIdx.x & 63;
    float v = (lane < 40) ? in[(size_t)rowi * 40 + lane] : -INFINITY;
    float m = v;
#pragma unroll
    for (int o = 32; o; o >>= 1) m = fmaxf(m, __shfl_xor(m, o));
    float ex = (lane < 40) ? expf(v - m) : 0.f;
    float s = ex;
#pragma unroll
    for (int o = 32; o; o >>= 1) s += __shfl_xor(s, o);
    if (lane < 40) out[(size_t)rowi * 40 + lane] = v - m - logf(s);
}

extern "C" void kernel_launch(void* const* d_in, const int* in_sizes, int n_in,
                              void* d_out, int out_size, void* d_ws, size_t ws_size,
                              hipStream_t stream) {
    const float* x  = (const float*)d_in[0];
    const int*   ei = (const int*)d_in[1];
    const float* W1 = (const float*)d_in[2];
    const float* b1 = (const float*)d_in[3];
    const float* W2 = (const float*)d_in[4];
    const float* b2 = (const float*)d_in[5];
    const float* W3 = (const float*)d_in[6];
    const float* b3 = (const float*)d_in[7];
    int N = in_sizes[0] / 128;
    int E = in_sizes[1] / 2;
    const int* row = ei;
    const int* col = ei + E;
    int NB = (N + 255) >> 8;

    char* ws = (char*)d_ws;
    size_t off = 0;
    auto alloc = [&](size_t bytes) {
        void* p = ws + off;
        off += (bytes + 255) & ~(size_t)255;
        return p;
    };
    unsigned short* hA = (unsigned short*)alloc((size_t)N * 128 * 2);
    unsigned short* hB = (unsigned short*)alloc((size_t)N * 128 * 2);
    float* t3    = (float*)alloc((size_t)N * 40 * 4);
    float* t3b   = (float*)alloc((size_t)N * 40 * 4);
    int*   esrc  = (int*)alloc((size_t)E * 4);
    int*   cptr  = (int*)alloc((size_t)N * 4);
    int*   cnt   = (int*)alloc((size_t)N * 4);
    float* dis   = (float*)alloc((size_t)N * 4);
    int*   bsum  = (int*)alloc(256 * 4);
    int*   bhist = (int*)alloc(512 * 4);
    int*   bbase = (int*)alloc(513 * 4);
    int*   bcur  = (int*)alloc(512 * 4);
    // binned staging (E*4B = 6.4 MB) aliases hB (25.6 MB): hB is first
    // written by agg1, long after k_fill2 consumed binned.
    unsigned* binned = (unsigned*)hB;

    // ---- CSR build (two-level counting sort) ----
    hipMemsetAsync(bhist, 0, 512 * 4, stream);
    k_bhist<<<256, 256, 0, stream>>>(col, E, NB, bhist);
    k_bscan<<<1, 512, 0, stream>>>(bhist, NB, E, bbase, bcur);
    k_bin2<<<256, 256, 0, stream>>>(row, col, E, bcur, binned);
    k_cntB<<<NB, 256, 0, stream>>>(binned, bbase, N, cnt);
    int B = (N + 1023) / 1024;
    k_bsum<<<B, 256, 0, stream>>>(cnt, N, bsum);
    k_sbsum<<<1, 128, 0, stream>>>(bsum, B);
    k_wptr<<<B, 256, 0, stream>>>(cnt, bsum, N, cptr, dis);
    k_fill2<<<NB, 256, 0, stream>>>(binned, bbase, cptr, N, esrc);

    // ---- layers ----
    int gb = (N + 63) / 64;
    int ab = (N + 3) / 4;
    k_gemm128_f32<<<gb, 256, 0, stream>>>(x, W1, hA, N);
    k_agg128<<<ab, 256, 0, stream>>>(hA, dis, cptr, cnt, esrc, b1, hB, 1, N);
    k_gemm128_bf16<<<gb, 256, 0, stream>>>(hB, W2, hA, N);
    k_agg128<<<ab, 256, 0, stream>>>(hA, dis, cptr, cnt, esrc, b2, hB, 1, N);
    k_gemm40<<<gb, 320, 0, stream>>>(hB, W3, t3, N);
    k_agg40<<<ab, 256, 0, stream>>>(t3, dis, cptr, cnt, esrc, b3, t3b, N);
    k_lsm<<<ab, 256, 0, stream>>>(t3b, (float*)d_out, N);
}

// Round 11
// 546.917 us; speedup vs baseline: 2.2614x; 1.0559x over previous
//
#include <hip/hip_runtime.h>
#include <hip/hip_bf16.h>
#include <math.h>

// ---------------------------------------------------------------------------
// 3-layer GCN, bf16 hidden activations (f32 accumulation everywhere).
// CSR build = two-level counting sort by 256-node bucket.
// Layer 3 reordered via linearity: agg(h@W3) == agg(h)@W3, so the last
// aggregation runs as a 128-wide bf16 agg (fast path) and the 40-wide GEMM
// (+bias) fuses log_softmax in its epilogue.
// ---------------------------------------------------------------------------

__device__ inline float bfu(unsigned short s) {
    return __uint_as_float((unsigned)s << 16);
}
__device__ inline float bf16lo(unsigned u) { return __uint_as_float(u << 16); }
__device__ inline float bf16hi(unsigned u) { return __uint_as_float(u & 0xFFFF0000u); }
__device__ inline unsigned packbf2(float a, float b) {
    __hip_bfloat16 x = __float2bfloat16(a), y = __float2bfloat16(b);
    unsigned short ux = *(unsigned short*)&x, uy = *(unsigned short*)&y;
    return (unsigned)ux | ((unsigned)uy << 16);
}

// ---- bucket histogram ----
__global__ __launch_bounds__(256) void k_bhist(const int* __restrict__ col, int E,
                                               int NB, int* __restrict__ bhist) {
    __shared__ int h[512];
    for (int j = threadIdx.x; j < 512; j += 256) h[j] = 0;
    __syncthreads();
    int chunk = (E + gridDim.x - 1) / gridDim.x;
    int lo = blockIdx.x * chunk;
    int hi = min(lo + chunk, E);
    for (int i = lo + threadIdx.x; i < hi; i += 256)
        atomicAdd(&h[col[i] >> 8], 1);
    __syncthreads();
    for (int j = threadIdx.x; j < NB; j += 256) {
        int v = h[j];
        if (v) atomicAdd(&bhist[j], v);
    }
}

// ---- exclusive scan of bucket counts ----
__global__ __launch_bounds__(512) void k_bscan(const int* __restrict__ bhist,
                                               int NB, int E,
                                               int* __restrict__ bbase,
                                               int* __restrict__ bcur) {
    __shared__ int sm[512];
    int t = threadIdx.x;
    int v = (t < NB) ? bhist[t] : 0;
    sm[t] = v;
    __syncthreads();
    for (int off = 1; off < 512; off <<= 1) {
        int u = (t >= off) ? sm[t - off] : 0;
        __syncthreads();
        sm[t] += u;
        __syncthreads();
    }
    if (t < NB) {
        int ex = sm[t] - v;
        bbase[t] = ex;
        bcur[t] = ex;
    }
    if (t == 0) bbase[NB] = E;
}

// ---- two-level binning ----
__global__ __launch_bounds__(256) void k_bin2(const int* __restrict__ row,
                                              const int* __restrict__ col, int E,
                                              int* __restrict__ bcur,
                                              unsigned* __restrict__ binned) {
    __shared__ int h[512];
    __shared__ int base[512];
    int t = threadIdx.x;
    for (int j = t; j < 512; j += 256) h[j] = 0;
    __syncthreads();
    int chunk = (E + gridDim.x - 1) / gridDim.x;
    int lo = blockIdx.x * chunk;
    int hi = min(lo + chunk, E);
    for (int i = lo + t; i < hi; i += 256)
        atomicAdd(&h[col[i] >> 8], 1);
    __syncthreads();
    for (int j = t; j < 512; j += 256) {
        int c = h[j];
        base[j] = c ? atomicAdd(&bcur[j], c) : 0;
    }
    __syncthreads();
    for (int i = lo + t; i < hi; i += 256) {
        int r = row[i], c = col[i];
        int p = atomicAdd(&base[c >> 8], 1);
        binned[p] = (unsigned)r | ((unsigned)(c & 255) << 24);
    }
}

// ---- per-node counts ----
__global__ __launch_bounds__(256) void k_cntB(const unsigned* __restrict__ binned,
                                              const int* __restrict__ bbase,
                                              int N, int* __restrict__ cnt) {
    int b = blockIdx.x, t = threadIdx.x;
    __shared__ int sc[256];
    sc[t] = 0;
    __syncthreads();
    int lo = bbase[b], hi = bbase[b + 1];
    for (int i = lo + t; i < hi; i += 256)
        atomicAdd(&sc[binned[i] >> 24], 1);
    __syncthreads();
    int node = b * 256 + t;
    if (node < N) cnt[node] = sc[t];
}

// ---- scan stage 1 ----
__global__ __launch_bounds__(256) void k_bsum(const int* __restrict__ cnt, int N,
                                              int* __restrict__ bsum) {
    int t = threadIdx.x;
    int base = blockIdx.x * 1024 + t * 4;
    int s = 0;
    if (base + 3 < N) {
        int4 v = *(const int4*)(cnt + base);
        s = v.x + v.y + v.z + v.w;
    } else {
        for (int j = 0; j < 4; ++j)
            if (base + j < N) s += cnt[base + j];
    }
#pragma unroll
    for (int off = 32; off; off >>= 1) s += __shfl_xor(s, off);
    __shared__ int ws[4];
    int lane = t & 63, w = t >> 6;
    if (lane == 0) ws[w] = s;
    __syncthreads();
    if (t == 0) bsum[blockIdx.x] = ws[0] + ws[1] + ws[2] + ws[3];
}

// ---- scan stage 2 ----
__global__ __launch_bounds__(128) void k_sbsum(int* __restrict__ bsum, int B) {
    __shared__ int sm[128];
    int t = threadIdx.x;
    int v = (t < B) ? bsum[t] : 0;
    sm[t] = v;
    __syncthreads();
    for (int off = 1; off < 128; off <<= 1) {
        int u = (t >= off) ? sm[t - off] : 0;
        __syncthreads();
        sm[t] += u;
        __syncthreads();
    }
    if (t < B) bsum[t] = sm[t] - v;
}

// ---- scan stage 3: ptr/dis ----
__global__ __launch_bounds__(256) void k_wptr(const int* __restrict__ cnt,
                                              const int* __restrict__ bsum, int N,
                                              int* __restrict__ ptr,
                                              float* __restrict__ dis) {
    int t = threadIdx.x;
    int base = blockIdx.x * 1024 + t * 4;
    int c[4];
    int s = 0;
    if (base + 3 < N) {
        int4 v = *(const int4*)(cnt + base);
        c[0] = v.x; c[1] = v.y; c[2] = v.z; c[3] = v.w;
        s = v.x + v.y + v.z + v.w;
    } else {
#pragma unroll
        for (int j = 0; j < 4; ++j) {
            c[j] = (base + j < N) ? cnt[base + j] : 0;
            s += c[j];
        }
    }
    int lane = t & 63, w = t >> 6;
    int incl = s;
#pragma unroll
    for (int off = 1; off < 64; off <<= 1) {
        int u = __shfl_up(incl, off);
        if (lane >= off) incl += u;
    }
    __shared__ int wsum[4];
    if (lane == 63) wsum[w] = incl;
    __syncthreads();
    int run = bsum[blockIdx.x] + (incl - s);
    for (int j = 0; j < w; ++j) run += wsum[j];
#pragma unroll
    for (int j = 0; j < 4; ++j) {
        int i = base + j;
        if (i < N) {
            ptr[i] = run;
            dis[i] = rsqrtf((float)(c[j] + 1));
            run += c[j];
        }
    }
}

// ---- CSR fill ----
__global__ __launch_bounds__(256) void k_fill2(const unsigned* __restrict__ binned,
                                               const int* __restrict__ bbase,
                                               const int* __restrict__ ptr, int N,
                                               int* __restrict__ esrc) {
    int b = blockIdx.x, t = threadIdx.x;
    __shared__ int lc[256];
    int node = b * 256 + t;
    lc[t] = (node < N) ? ptr[node] : 0;
    __syncthreads();
    int lo = bbase[b], hi = bbase[b + 1];
    for (int i = lo + t; i < hi; i += 256) {
        unsigned e = binned[i];
        int p = atomicAdd(&lc[e >> 24], 1);
        esrc[p] = (int)(e & 0xFFFFFFu);
    }
}

// ---- GEMM layer1: X f32 [M][128] @ W f32 -> Y bf16 [M][128] ----
__global__ __launch_bounds__(256) void k_gemm128_f32(const float* __restrict__ X,
                                                     const float* __restrict__ W,
                                                     unsigned short* __restrict__ Y,
                                                     int M) {
    __shared__ float wsm[64 * 128];
    __shared__ float xs[64 * 68];
    int t = threadIdx.x;
    int row0 = blockIdx.x * 64;
    int cg = t & 15, rg = t >> 4;
    float acc[4][8];
#pragma unroll
    for (int a = 0; a < 4; ++a)
#pragma unroll
        for (int b = 0; b < 8; ++b) acc[a][b] = 0.f;

    for (int kp = 0; kp < 2; ++kp) {
        const float4* W4 = (const float4*)W;
        float4* wd = (float4*)wsm;
#pragma unroll
        for (int i = 0; i < 8; ++i) {
            int idx = t + i * 256;
            wd[idx] = W4[kp * 2048 + idx];
        }
        const float4* X4 = (const float4*)X;
#pragma unroll
        for (int i = 0; i < 4; ++i) {
            int idx = t + i * 256;
            int r = idx >> 4, c4 = idx & 15;
            float4 v = {0.f, 0.f, 0.f, 0.f};
            if (row0 + r < M) v = X4[(size_t)(row0 + r) * 32 + kp * 16 + c4];
            float* dst = &xs[r * 68 + c4 * 4];
            dst[0] = v.x; dst[1] = v.y; dst[2] = v.z; dst[3] = v.w;
        }
        __syncthreads();
#pragma unroll 4
        for (int k = 0; k < 64; ++k) {
            float a0 = xs[(rg * 4 + 0) * 68 + k];
            float a1 = xs[(rg * 4 + 1) * 68 + k];
            float a2 = xs[(rg * 4 + 2) * 68 + k];
            float a3 = xs[(rg * 4 + 3) * 68 + k];
            const float* wr = &wsm[k * 128 + cg * 8];
            float4 w0 = *(const float4*)wr;
            float4 w1 = *(const float4*)(wr + 4);
            float wv[8] = {w0.x, w0.y, w0.z, w0.w, w1.x, w1.y, w1.z, w1.w};
#pragma unroll
            for (int b = 0; b < 8; ++b) {
                acc[0][b] = fmaf(a0, wv[b], acc[0][b]);
                acc[1][b] = fmaf(a1, wv[b], acc[1][b]);
                acc[2][b] = fmaf(a2, wv[b], acc[2][b]);
                acc[3][b] = fmaf(a3, wv[b], acc[3][b]);
            }
        }
        __syncthreads();
    }
#pragma unroll
    for (int a = 0; a < 4; ++a) {
        int r = row0 + rg * 4 + a;
        if (r < M) {
            uint4 o;
            o.x = packbf2(acc[a][0], acc[a][1]);
            o.y = packbf2(acc[a][2], acc[a][3]);
            o.z = packbf2(acc[a][4], acc[a][5]);
            o.w = packbf2(acc[a][6], acc[a][7]);
            *(uint4*)&Y[(size_t)r * 128 + cg * 8] = o;
        }
    }
}

// ---- GEMM layer2: X bf16 [M][128] @ W f32 -> Y bf16 [M][128] ----
__global__ __launch_bounds__(256) void k_gemm128_bf16(const unsigned short* __restrict__ X,
                                                      const float* __restrict__ W,
                                                      unsigned short* __restrict__ Y,
                                                      int M) {
    __shared__ float wsm[64 * 128];
    __shared__ float xs[64 * 68];
    int t = threadIdx.x;
    int row0 = blockIdx.x * 64;
    int cg = t & 15, rg = t >> 4;
    float acc[4][8];
#pragma unroll
    for (int a = 0; a < 4; ++a)
#pragma unroll
        for (int b = 0; b < 8; ++b) acc[a][b] = 0.f;

    for (int kp = 0; kp < 2; ++kp) {
        const float4* W4 = (const float4*)W;
        float4* wd = (float4*)wsm;
#pragma unroll
        for (int i = 0; i < 8; ++i) {
            int idx = t + i * 256;
            wd[idx] = W4[kp * 2048 + idx];
        }
        const ushort4* X4 = (const ushort4*)X;
#pragma unroll
        for (int i = 0; i < 4; ++i) {
            int idx = t + i * 256;
            int r = idx >> 4, c4 = idx & 15;
            float v0 = 0.f, v1 = 0.f, v2 = 0.f, v3 = 0.f;
            if (row0 + r < M) {
                ushort4 v = X4[(size_t)(row0 + r) * 32 + kp * 16 + c4];
                v0 = bfu(v.x); v1 = bfu(v.y); v2 = bfu(v.z); v3 = bfu(v.w);
            }
            float* dst = &xs[r * 68 + c4 * 4];
            dst[0] = v0; dst[1] = v1; dst[2] = v2; dst[3] = v3;
        }
        __syncthreads();
#pragma unroll 4
        for (int k = 0; k < 64; ++k) {
            float a0 = xs[(rg * 4 + 0) * 68 + k];
            float a1 = xs[(rg * 4 + 1) * 68 + k];
            float a2 = xs[(rg * 4 + 2) * 68 + k];
            float a3 = xs[(rg * 4 + 3) * 68 + k];
            const float* wr = &wsm[k * 128 + cg * 8];
            float4 w0 = *(const float4*)wr;
            float4 w1 = *(const float4*)(wr + 4);
            float wv[8] = {w0.x, w0.y, w0.z, w0.w, w1.x, w1.y, w1.z, w1.w};
#pragma unroll
            for (int b = 0; b < 8; ++b) {
                acc[0][b] = fmaf(a0, wv[b], acc[0][b]);
                acc[1][b] = fmaf(a1, wv[b], acc[1][b]);
                acc[2][b] = fmaf(a2, wv[b], acc[2][b]);
                acc[3][b] = fmaf(a3, wv[b], acc[3][b]);
            }
        }
        __syncthreads();
    }
#pragma unroll
    for (int a = 0; a < 4; ++a) {
        int r = row0 + rg * 4 + a;
        if (r < M) {
            uint4 o;
            o.x = packbf2(acc[a][0], acc[a][1]);
            o.y = packbf2(acc[a][2], acc[a][3]);
            o.z = packbf2(acc[a][4], acc[a][5]);
            o.w = packbf2(acc[a][6], acc[a][7]);
            *(uint4*)&Y[(size_t)r * 128 + cg * 8] = o;
        }
    }
}

// ---- layer3 fused: Y = log_softmax(X bf16 [M][128] @ W3 [128][40] + b3) ----
__global__ __launch_bounds__(320) void k_gemm40f(const unsigned short* __restrict__ X,
                                                 const float* __restrict__ W,
                                                 const float* __restrict__ bias,
                                                 float* __restrict__ out, int M) {
    __shared__ float wsm[128 * 40];   // 20 KB
    __shared__ float xs[64 * 133];    // 34 KB
    __shared__ float osm[64 * 40];    // 10 KB
    __shared__ float rm[64], rls[64];
    int t = threadIdx.x;
    int row0 = blockIdx.x * 64;
    for (int idx = t; idx < 128 * 40; idx += 320) wsm[idx] = W[idx];
    const ushort4* X4 = (const ushort4*)X;
    for (int idx = t; idx < 2048; idx += 320) {
        int r = idx >> 5, c4 = idx & 31;
        float v0 = 0.f, v1 = 0.f, v2 = 0.f, v3 = 0.f;
        if (row0 + r < M) {
            ushort4 v = X4[(size_t)(row0 + r) * 32 + c4];
            v0 = bfu(v.x); v1 = bfu(v.y); v2 = bfu(v.z); v3 = bfu(v.w);
        }
        float* dst = &xs[r * 133 + c4 * 4];
        dst[0] = v0; dst[1] = v1; dst[2] = v2; dst[3] = v3;
    }
    __syncthreads();
    int lane = t & 63, cg = t >> 6;   // cg 0..4, 8 cols each
    float acc[8];
#pragma unroll
    for (int b = 0; b < 8; ++b) acc[b] = 0.f;
#pragma unroll 4
    for (int k = 0; k < 128; ++k) {
        float a = xs[lane * 133 + k];
        const float* wr = &wsm[k * 40 + cg * 8];
        float4 w0 = *(const float4*)wr;
        float4 w1 = *(const float4*)(wr + 4);
        acc[0] = fmaf(a, w0.x, acc[0]); acc[1] = fmaf(a, w0.y, acc[1]);
        acc[2] = fmaf(a, w0.z, acc[2]); acc[3] = fmaf(a, w0.w, acc[3]);
        acc[4] = fmaf(a, w1.x, acc[4]); acc[5] = fmaf(a, w1.y, acc[5]);
        acc[6] = fmaf(a, w1.z, acc[6]); acc[7] = fmaf(a, w1.w, acc[7]);
    }
#pragma unroll
    for (int b = 0; b < 8; ++b) {
        acc[b] += bias[cg * 8 + b];
        osm[lane * 40 + cg * 8 + b] = acc[b];
    }
    __syncthreads();
    if (t < 64) {
        const float* rowv = &osm[t * 40];
        float m = rowv[0];
        for (int k = 1; k < 40; ++k) m = fmaxf(m, rowv[k]);
        float s = 0.f;
        for (int k = 0; k < 40; ++k) s += expf(rowv[k] - m);
        rm[t] = m;
        rls[t] = logf(s);
    }
    __syncthreads();
    int r = row0 + lane;
    if (r < M) {
        float sub = rm[lane] + rls[lane];
        float4* dst = (float4*)&out[(size_t)r * 40 + cg * 8];
        float4 o0 = {acc[0] - sub, acc[1] - sub, acc[2] - sub, acc[3] - sub};
        float4 o1 = {acc[4] - sub, acc[5] - sub, acc[6] - sub, acc[7] - sub};
        dst[0] = o0;
        dst[1] = o1;
    }
}

// ---- aggregation, 128 bf16 features: one wave per node, lane owns 2 ----
__global__ __launch_bounds__(256) void k_agg128(const unsigned short* __restrict__ h,
                                                const float* __restrict__ dis,
                                                const int* __restrict__ ptr,
                                                const int* __restrict__ cnt,
                                                const int* __restrict__ esrc,
                                                const float* __restrict__ bias,
                                                unsigned short* __restrict__ out,
                                                int relu, int N) {
    int node = blockIdx.x * 4 + (threadIdx.x >> 6);
    if (node >= N) return;
    int lane = threadIdx.x & 63;
    float di = dis[node];
    const unsigned* h32 = (const unsigned*)h;
    unsigned su = h32[(size_t)node * 64 + lane];
    float w = di * di;
    float ax = bf16lo(su) * w, ay = bf16hi(su) * w;
    int start = ptr[node], c = cnt[node];
    for (int base = 0; base < c; base += 64) {
        int m = min(64, c - base);
        int e = 0;
        float dsl = 0.f;
        if (lane < m) {
            e = esrc[start + base + lane];
            dsl = dis[e];
        }
        int j = 0;
        for (; j + 2 <= m; j += 2) {
            int sA = __shfl(e, j), sB = __shfl(e, j + 1);
            float scA = __shfl(dsl, j) * di;
            float scB = __shfl(dsl, j + 1) * di;
            unsigned uA = h32[(size_t)sA * 64 + lane];
            unsigned uB = h32[(size_t)sB * 64 + lane];
            ax = fmaf(bf16lo(uA), scA, ax); ay = fmaf(bf16hi(uA), scA, ay);
            ax = fmaf(bf16lo(uB), scB, ax); ay = fmaf(bf16hi(uB), scB, ay);
        }
        if (j < m) {
            int sA = __shfl(e, j);
            float scA = __shfl(dsl, j) * di;
            unsigned uA = h32[(size_t)sA * 64 + lane];
            ax = fmaf(bf16lo(uA), scA, ax); ay = fmaf(bf16hi(uA), scA, ay);
        }
    }
    if (bias) {
        float2 b = ((const float2*)bias)[lane];
        ax += b.x; ay += b.y;
    }
    if (relu) { ax = fmaxf(ax, 0.f); ay = fmaxf(ay, 0.f); }
    ((unsigned*)out)[(size_t)node * 64 + lane] = packbf2(ax, ay);
}

extern "C" void kernel_launch(void* const* d_in, const int* in_sizes, int n_in,
                              void* d_out, int out_size, void* d_ws, size_t ws_size,
                              hipStream_t stream) {
    const float* x  = (const float*)d_in[0];
    const int*   ei = (const int*)d_in[1];
    const float* W1 = (const float*)d_in[2];
    const float* b1 = (const float*)d_in[3];
    const float* W2 = (const float*)d_in[4];
    const float* b2 = (const float*)d_in[5];
    const float* W3 = (const float*)d_in[6];
    const float* b3 = (const float*)d_in[7];
    int N = in_sizes[0] / 128;
    int E = in_sizes[1] / 2;
    const int* row = ei;
    const int* col = ei + E;
    int NB = (N + 255) >> 8;

    char* ws = (char*)d_ws;
    size_t off = 0;
    auto alloc = [&](size_t bytes) {
        void* p = ws + off;
        off += (bytes + 255) & ~(size_t)255;
        return p;
    };
    unsigned short* hA = (unsigned short*)alloc((size_t)N * 128 * 2);
    unsigned short* hB = (unsigned short*)alloc((size_t)N * 128 * 2);
    int*   esrc  = (int*)alloc((size_t)E * 4);
    int*   cptr  = (int*)alloc((size_t)N * 4);
    int*   cnt   = (int*)alloc((size_t)N * 4);
    float* dis   = (float*)alloc((size_t)N * 4);
    int*   bsum  = (int*)alloc(256 * 4);
    int*   bhist = (int*)alloc(512 * 4);
    int*   bbase = (int*)alloc(513 * 4);
    int*   bcur  = (int*)alloc(512 * 4);
    // binned staging (E*4B = 6.4 MB) aliases hB (25.6 MB): hB is first
    // written by agg1, long after k_fill2 consumed binned.
    unsigned* binned = (unsigned*)hB;

    // ---- CSR build (two-level counting sort) ----
    hipMemsetAsync(bhist, 0, 512 * 4, stream);
    k_bhist<<<256, 256, 0, stream>>>(col, E, NB, bhist);
    k_bscan<<<1, 512, 0, stream>>>(bhist, NB, E, bbase, bcur);
    k_bin2<<<256, 256, 0, stream>>>(row, col, E, bcur, binned);
    k_cntB<<<NB, 256, 0, stream>>>(binned, bbase, N, cnt);
    int B = (N + 1023) / 1024;
    k_bsum<<<B, 256, 0, stream>>>(cnt, N, bsum);
    k_sbsum<<<1, 128, 0, stream>>>(bsum, B);
    k_wptr<<<B, 256, 0, stream>>>(cnt, bsum, N, cptr, dis);
    k_fill2<<<NB, 256, 0, stream>>>(binned, bbase, cptr, N, esrc);

    // ---- layers ----
    int gb = (N + 63) / 64;
    int ab = (N + 3) / 4;
    k_gemm128_f32<<<gb, 256, 0, stream>>>(x, W1, hA, N);
    k_agg128<<<ab, 256, 0, stream>>>(hA, dis, cptr, cnt, esrc, b1, hB, 1, N);
    k_gemm128_bf16<<<gb, 256, 0, stream>>>(hB, W2, hA, N);
    k_agg128<<<ab, 256, 0, stream>>>(hA, dis, cptr, cnt, esrc, b2, hB, 1, N);
    k_agg128<<<ab, 256, 0, stream>>>(hB, dis, cptr, cnt, esrc, nullptr, hA, 0, N);
    k_gemm40f<<<gb, 320, 0, stream>>>(hA, W3, b3, (float*)d_out, N);
}

// Round 14
// 525.227 us; speedup vs baseline: 2.3548x; 1.0413x over previous
//
#include <hip/hip_runtime.h>
#include <hip/hip_bf16.h>
#include <math.h>

// ---------------------------------------------------------------------------
// 3-layer GCN, bf16 hidden activations (f32 accumulation everywhere).
// CSR build = two-level counting sort by 256-node bucket.
// Layer 3 reordered via linearity: agg(h@W3) == agg(h)@W3.
// agg128: half-wave edge split — lanes 0-31 do edge 2j, lanes 32-63 edge
// 2j+1, 8B/lane loads, x2 unroll = 4 rows in flight per wave.
// ---------------------------------------------------------------------------

__device__ inline float bfu(unsigned short s) {
    return __uint_as_float((unsigned)s << 16);
}
__device__ inline float bf16lo(unsigned u) { return __uint_as_float(u << 16); }
__device__ inline float bf16hi(unsigned u) { return __uint_as_float(u & 0xFFFF0000u); }
__device__ inline unsigned packbf2(float a, float b) {
    __hip_bfloat16 x = __float2bfloat16(a), y = __float2bfloat16(b);
    unsigned short ux = *(unsigned short*)&x, uy = *(unsigned short*)&y;
    return (unsigned)ux | ((unsigned)uy << 16);
}

// ---- bucket histogram ----
__global__ __launch_bounds__(256) void k_bhist(const int* __restrict__ col, int E,
                                               int NB, int* __restrict__ bhist) {
    __shared__ int h[512];
    for (int j = threadIdx.x; j < 512; j += 256) h[j] = 0;
    __syncthreads();
    int chunk = (E + gridDim.x - 1) / gridDim.x;
    int lo = blockIdx.x * chunk;
    int hi = min(lo + chunk, E);
    for (int i = lo + threadIdx.x; i < hi; i += 256)
        atomicAdd(&h[col[i] >> 8], 1);
    __syncthreads();
    for (int j = threadIdx.x; j < NB; j += 256) {
        int v = h[j];
        if (v) atomicAdd(&bhist[j], v);
    }
}

// ---- exclusive scan of bucket counts ----
__global__ __launch_bounds__(512) void k_bscan(const int* __restrict__ bhist,
                                               int NB, int E,
                                               int* __restrict__ bbase,
                                               int* __restrict__ bcur) {
    __shared__ int sm[512];
    int t = threadIdx.x;
    int v = (t < NB) ? bhist[t] : 0;
    sm[t] = v;
    __syncthreads();
    for (int off = 1; off < 512; off <<= 1) {
        int u = (t >= off) ? sm[t - off] : 0;
        __syncthreads();
        sm[t] += u;
        __syncthreads();
    }
    if (t < NB) {
        int ex = sm[t] - v;
        bbase[t] = ex;
        bcur[t] = ex;
    }
    if (t == 0) bbase[NB] = E;
}

// ---- two-level binning ----
__global__ __launch_bounds__(256) void k_bin2(const int* __restrict__ row,
                                              const int* __restrict__ col, int E,
                                              int* __restrict__ bcur,
                                              unsigned* __restrict__ binned) {
    __shared__ int h[512];
    __shared__ int base[512];
    int t = threadIdx.x;
    for (int j = t; j < 512; j += 256) h[j] = 0;
    __syncthreads();
    int chunk = (E + gridDim.x - 1) / gridDim.x;
    int lo = blockIdx.x * chunk;
    int hi = min(lo + chunk, E);
    for (int i = lo + t; i < hi; i += 256)
        atomicAdd(&h[col[i] >> 8], 1);
    __syncthreads();
    for (int j = t; j < 512; j += 256) {
        int c = h[j];
        base[j] = c ? atomicAdd(&bcur[j], c) : 0;
    }
    __syncthreads();
    for (int i = lo + t; i < hi; i += 256) {
        int r = row[i], c = col[i];
        int p = atomicAdd(&base[c >> 8], 1);
        binned[p] = (unsigned)r | ((unsigned)(c & 255) << 24);
    }
}

// ---- per-node counts ----
__global__ __launch_bounds__(256) void k_cntB(const unsigned* __restrict__ binned,
                                              const int* __restrict__ bbase,
                                              int N, int* __restrict__ cnt) {
    int b = blockIdx.x, t = threadIdx.x;
    __shared__ int sc[256];
    sc[t] = 0;
    __syncthreads();
    int lo = bbase[b], hi = bbase[b + 1];
    for (int i = lo + t; i < hi; i += 256)
        atomicAdd(&sc[binned[i] >> 24], 1);
    __syncthreads();
    int node = b * 256 + t;
    if (node < N) cnt[node] = sc[t];
}

// ---- scan stage 1 ----
__global__ __launch_bounds__(256) void k_bsum(const int* __restrict__ cnt, int N,
                                              int* __restrict__ bsum) {
    int t = threadIdx.x;
    int base = blockIdx.x * 1024 + t * 4;
    int s = 0;
    if (base + 3 < N) {
        int4 v = *(const int4*)(cnt + base);
        s = v.x + v.y + v.z + v.w;
    } else {
        for (int j = 0; j < 4; ++j)
            if (base + j < N) s += cnt[base + j];
    }
#pragma unroll
    for (int off = 32; off; off >>= 1) s += __shfl_xor(s, off);
    __shared__ int ws[4];
    int lane = t & 63, w = t >> 6;
    if (lane == 0) ws[w] = s;
    __syncthreads();
    if (t == 0) bsum[blockIdx.x] = ws[0] + ws[1] + ws[2] + ws[3];
}

// ---- scan stage 2 ----
__global__ __launch_bounds__(128) void k_sbsum(int* __restrict__ bsum, int B) {
    __shared__ int sm[128];
    int t = threadIdx.x;
    int v = (t < B) ? bsum[t] : 0;
    sm[t] = v;
    __syncthreads();
    for (int off = 1; off < 128; off <<= 1) {
        int u = (t >= off) ? sm[t - off] : 0;
        __syncthreads();
        sm[t] += u;
        __syncthreads();
    }
    if (t < B) bsum[t] = sm[t] - v;
}

// ---- scan stage 3: ptr/dis ----
__global__ __launch_bounds__(256) void k_wptr(const int* __restrict__ cnt,
                                              const int* __restrict__ bsum, int N,
                                              int* __restrict__ ptr,
                                              float* __restrict__ dis) {
    int t = threadIdx.x;
    int base = blockIdx.x * 1024 + t * 4;
    int c[4];
    int s = 0;
    if (base + 3 < N) {
        int4 v = *(const int4*)(cnt + base);
        c[0] = v.x; c[1] = v.y; c[2] = v.z; c[3] = v.w;
        s = v.x + v.y + v.z + v.w;
    } else {
#pragma unroll
        for (int j = 0; j < 4; ++j) {
            c[j] = (base + j < N) ? cnt[base + j] : 0;
            s += c[j];
        }
    }
    int lane = t & 63, w = t >> 6;
    int incl = s;
#pragma unroll
    for (int off = 1; off < 64; off <<= 1) {
        int u = __shfl_up(incl, off);
        if (lane >= off) incl += u;
    }
    __shared__ int wsum[4];
    if (lane == 63) wsum[w] = incl;
    __syncthreads();
    int run = bsum[blockIdx.x] + (incl - s);
    for (int j = 0; j < w; ++j) run += wsum[j];
#pragma unroll
    for (int j = 0; j < 4; ++j) {
        int i = base + j;
        if (i < N) {
            ptr[i] = run;
            dis[i] = rsqrtf((float)(c[j] + 1));
            run += c[j];
        }
    }
}

// ---- CSR fill ----
__global__ __launch_bounds__(256) void k_fill2(const unsigned* __restrict__ binned,
                                               const int* __restrict__ bbase,
                                               const int* __restrict__ ptr, int N,
                                               int* __restrict__ esrc) {
    int b = blockIdx.x, t = threadIdx.x;
    __shared__ int lc[256];
    int node = b * 256 + t;
    lc[t] = (node < N) ? ptr[node] : 0;
    __syncthreads();
    int lo = bbase[b], hi = bbase[b + 1];
    for (int i = lo + t; i < hi; i += 256) {
        unsigned e = binned[i];
        int p = atomicAdd(&lc[e >> 24], 1);
        esrc[p] = (int)(e & 0xFFFFFFu);
    }
}

// ---- GEMM layer1: X f32 [M][128] @ W f32 -> Y bf16 [M][128] ----
__global__ __launch_bounds__(256) void k_gemm128_f32(const float* __restrict__ X,
                                                     const float* __restrict__ W,
                                                     unsigned short* __restrict__ Y,
                                                     int M) {
    __shared__ float wsm[64 * 128];
    __shared__ float xs[64 * 68];
    int t = threadIdx.x;
    int row0 = blockIdx.x * 64;
    int cg = t & 15, rg = t >> 4;
    float acc[4][8];
#pragma unroll
    for (int a = 0; a < 4; ++a)
#pragma unroll
        for (int b = 0; b < 8; ++b) acc[a][b] = 0.f;

    for (int kp = 0; kp < 2; ++kp) {
        const float4* W4 = (const float4*)W;
        float4* wd = (float4*)wsm;
#pragma unroll
        for (int i = 0; i < 8; ++i) {
            int idx = t + i * 256;
            wd[idx] = W4[kp * 2048 + idx];
        }
        const float4* X4 = (const float4*)X;
#pragma unroll
        for (int i = 0; i < 4; ++i) {
            int idx = t + i * 256;
            int r = idx >> 4, c4 = idx & 15;
            float4 v = {0.f, 0.f, 0.f, 0.f};
            if (row0 + r < M) v = X4[(size_t)(row0 + r) * 32 + kp * 16 + c4];
            float* dst = &xs[r * 68 + c4 * 4];
            dst[0] = v.x; dst[1] = v.y; dst[2] = v.z; dst[3] = v.w;
        }
        __syncthreads();
#pragma unroll 4
        for (int k = 0; k < 64; ++k) {
            float a0 = xs[(rg * 4 + 0) * 68 + k];
            float a1 = xs[(rg * 4 + 1) * 68 + k];
            float a2 = xs[(rg * 4 + 2) * 68 + k];
            float a3 = xs[(rg * 4 + 3) * 68 + k];
            const float* wr = &wsm[k * 128 + cg * 8];
            float4 w0 = *(const float4*)wr;
            float4 w1 = *(const float4*)(wr + 4);
            float wv[8] = {w0.x, w0.y, w0.z, w0.w, w1.x, w1.y, w1.z, w1.w};
#pragma unroll
            for (int b = 0; b < 8; ++b) {
                acc[0][b] = fmaf(a0, wv[b], acc[0][b]);
                acc[1][b] = fmaf(a1, wv[b], acc[1][b]);
                acc[2][b] = fmaf(a2, wv[b], acc[2][b]);
                acc[3][b] = fmaf(a3, wv[b], acc[3][b]);
            }
        }
        __syncthreads();
    }
#pragma unroll
    for (int a = 0; a < 4; ++a) {
        int r = row0 + rg * 4 + a;
        if (r < M) {
            uint4 o;
            o.x = packbf2(acc[a][0], acc[a][1]);
            o.y = packbf2(acc[a][2], acc[a][3]);
            o.z = packbf2(acc[a][4], acc[a][5]);
            o.w = packbf2(acc[a][6], acc[a][7]);
            *(uint4*)&Y[(size_t)r * 128 + cg * 8] = o;
        }
    }
}

// ---- GEMM layer2: X bf16 [M][128] @ W f32 -> Y bf16 [M][128] ----
__global__ __launch_bounds__(256) void k_gemm128_bf16(const unsigned short* __restrict__ X,
                                                      const float* __restrict__ W,
                                                      unsigned short* __restrict__ Y,
                                                      int M) {
    __shared__ float wsm[64 * 128];
    __shared__ float xs[64 * 68];
    int t = threadIdx.x;
    int row0 = blockIdx.x * 64;
    int cg = t & 15, rg = t >> 4;
    float acc[4][8];
#pragma unroll
    for (int a = 0; a < 4; ++a)
#pragma unroll
        for (int b = 0; b < 8; ++b) acc[a][b] = 0.f;

    for (int kp = 0; kp < 2; ++kp) {
        const float4* W4 = (const float4*)W;
        float4* wd = (float4*)wsm;
#pragma unroll
        for (int i = 0; i < 8; ++i) {
            int idx = t + i * 256;
            wd[idx] = W4[kp * 2048 + idx];
        }
        const ushort4* X4 = (const ushort4*)X;
#pragma unroll
        for (int i = 0; i < 4; ++i) {
            int idx = t + i * 256;
            int r = idx >> 4, c4 = idx & 15;
            float v0 = 0.f, v1 = 0.f, v2 = 0.f, v3 = 0.f;
            if (row0 + r < M) {
                ushort4 v = X4[(size_t)(row0 + r) * 32 + kp * 16 + c4];
                v0 = bfu(v.x); v1 = bfu(v.y); v2 = bfu(v.z); v3 = bfu(v.w);
            }
            float* dst = &xs[r * 68 + c4 * 4];
            dst[0] = v0; dst[1] = v1; dst[2] = v2; dst[3] = v3;
        }
        __syncthreads();
#pragma unroll 4
        for (int k = 0; k < 64; ++k) {
            float a0 = xs[(rg * 4 + 0) * 68 + k];
            float a1 = xs[(rg * 4 + 1) * 68 + k];
            float a2 = xs[(rg * 4 + 2) * 68 + k];
            float a3 = xs[(rg * 4 + 3) * 68 + k];
            const float* wr = &wsm[k * 128 + cg * 8];
            float4 w0 = *(const float4*)wr;
            float4 w1 = *(const float4*)(wr + 4);
            float wv[8] = {w0.x, w0.y, w0.z, w0.w, w1.x, w1.y, w1.z, w1.w};
#pragma unroll
            for (int b = 0; b < 8; ++b) {
                acc[0][b] = fmaf(a0, wv[b], acc[0][b]);
                acc[1][b] = fmaf(a1, wv[b], acc[1][b]);
                acc[2][b] = fmaf(a2, wv[b], acc[2][b]);
                acc[3][b] = fmaf(a3, wv[b], acc[3][b]);
            }
        }
        __syncthreads();
    }
#pragma unroll
    for (int a = 0; a < 4; ++a) {
        int r = row0 + rg * 4 + a;
        if (r < M) {
            uint4 o;
            o.x = packbf2(acc[a][0], acc[a][1]);
            o.y = packbf2(acc[a][2], acc[a][3]);
            o.z = packbf2(acc[a][4], acc[a][5]);
            o.w = packbf2(acc[a][6], acc[a][7]);
            *(uint4*)&Y[(size_t)r * 128 + cg * 8] = o;
        }
    }
}

// ---- layer3 fused: Y = log_softmax(X bf16 [M][128] @ W3 [128][40] + b3) ----
__global__ __launch_bounds__(320) void k_gemm40f(const unsigned short* __restrict__ X,
                                                 const float* __restrict__ W,
                                                 const float* __restrict__ bias,
                                                 float* __restrict__ out, int M) {
    __shared__ float wsm[128 * 40];   // 20 KB
    __shared__ float xs[64 * 133];    // 34 KB
    __shared__ float osm[64 * 40];    // 10 KB
    __shared__ float rm[64], rls[64];
    int t = threadIdx.x;
    int row0 = blockIdx.x * 64;
    for (int idx = t; idx < 128 * 40; idx += 320) wsm[idx] = W[idx];
    const ushort4* X4 = (const ushort4*)X;
    for (int idx = t; idx < 2048; idx += 320) {
        int r = idx >> 5, c4 = idx & 31;
        float v0 = 0.f, v1 = 0.f, v2 = 0.f, v3 = 0.f;
        if (row0 + r < M) {
            ushort4 v = X4[(size_t)(row0 + r) * 32 + c4];
            v0 = bfu(v.x); v1 = bfu(v.y); v2 = bfu(v.z); v3 = bfu(v.w);
        }
        float* dst = &xs[r * 133 + c4 * 4];
        dst[0] = v0; dst[1] = v1; dst[2] = v2; dst[3] = v3;
    }
    __syncthreads();
    int lane = t & 63, cg = t >> 6;   // cg 0..4, 8 cols each
    float acc[8];
#pragma unroll
    for (int b = 0; b < 8; ++b) acc[b] = 0.f;
#pragma unroll 4
    for (int k = 0; k < 128; ++k) {
        float a = xs[lane * 133 + k];
        const float* wr = &wsm[k * 40 + cg * 8];
        float4 w0 = *(const float4*)wr;
        float4 w1 = *(const float4*)(wr + 4);
        acc[0] = fmaf(a, w0.x, acc[0]); acc[1] = fmaf(a, w0.y, acc[1]);
        acc[2] = fmaf(a, w0.z, acc[2]); acc[3] = fmaf(a, w0.w, acc[3]);
        acc[4] = fmaf(a, w1.x, acc[4]); acc[5] = fmaf(a, w1.y, acc[5]);
        acc[6] = fmaf(a, w1.z, acc[6]); acc[7] = fmaf(a, w1.w, acc[7]);
    }
#pragma unroll
    for (int b = 0; b < 8; ++b) {
        acc[b] += bias[cg * 8 + b];
        osm[lane * 40 + cg * 8 + b] = acc[b];
    }
    __syncthreads();
    if (t < 64) {
        const float* rowv = &osm[t * 40];
        float m = rowv[0];
        for (int k = 1; k < 40; ++k) m = fmaxf(m, rowv[k]);
        float s = 0.f;
        for (int k = 0; k < 40; ++k) s += expf(rowv[k] - m);
        rm[t] = m;
        rls[t] = logf(s);
    }
    __syncthreads();
    int r = row0 + lane;
    if (r < M) {
        float sub = rm[lane] + rls[lane];
        float4* dst = (float4*)&out[(size_t)r * 40 + cg * 8];
        float4 o0 = {acc[0] - sub, acc[1] - sub, acc[2] - sub, acc[3] - sub};
        float4 o1 = {acc[4] - sub, acc[5] - sub, acc[6] - sub, acc[7] - sub};
        dst[0] = o0;
        dst[1] = o1;
    }
}

// ---- aggregation, 128 bf16: half-wave edge split, 8B/lane, x2 unroll ----
// Lane l<32 handles edge (j), lane>=32 edge (j+1); lane k=l&31 owns
// features [4k,4k+4). Halves combined at the end via shfl_xor(32).
__global__ __launch_bounds__(256) void k_agg128(const unsigned short* __restrict__ h,
                                                const float* __restrict__ dis,
                                                const int* __restrict__ ptr,
                                                const int* __restrict__ cnt,
                                                const int* __restrict__ esrc,
                                                const float* __restrict__ bias,
                                                unsigned short* __restrict__ out,
                                                int relu, int N) {
    int node = blockIdx.x * 4 + (threadIdx.x >> 6);
    if (node >= N) return;
    int lane = threadIdx.x & 63;
    int half = lane >> 5;      // 0 or 1
    int k = lane & 31;         // uint2 index within row
    float di = dis[node];
    const uint2* h64 = (const uint2*)h;
    float a0 = 0.f, a1 = 0.f, a2 = 0.f, a3 = 0.f;
    if (half == 0) {           // self term on low half only
        uint2 su = h64[(size_t)node * 32 + k];
        float w = di * di;
        a0 = bf16lo(su.x) * w; a1 = bf16hi(su.x) * w;
        a2 = bf16lo(su.y) * w; a3 = bf16hi(su.y) * w;
    }
    int start = ptr[node], c = cnt[node];
    for (int base = 0; base < c; base += 64) {
        int m = min(64, c - base);
        int e = 0;
        float dsl = 0.f;
        if (lane < m) {
            e = esrc[start + base + lane];
            dsl = dis[e];
        }
        int jb = 0;
        for (; jb + 4 <= m; jb += 4) {
            int iA = jb + half, iB = jb + 2 + half;
            int sA = __shfl(e, iA), sB = __shfl(e, iB);
            float scA = __shfl(dsl, iA) * di;
            float scB = __shfl(dsl, iB) * di;
            uint2 vA = h64[(size_t)sA * 32 + k];
            uint2 vB = h64[(size_t)sB * 32 + k];
            a0 = fmaf(bf16lo(vA.x), scA, a0); a1 = fmaf(bf16hi(vA.x), scA, a1);
            a2 = fmaf(bf16lo(vA.y), scA, a2); a3 = fmaf(bf16hi(vA.y), scA, a3);
            a0 = fmaf(bf16lo(vB.x), scB, a0); a1 = fmaf(bf16hi(vB.x), scB, a1);
            a2 = fmaf(bf16lo(vB.y), scB, a2); a3 = fmaf(bf16hi(vB.y), scB, a3);
        }
        for (; jb < m; jb += 2) {
            int iA = jb + half;
            // iA may be >= m for the high half on an odd tail: e defaults to
            // 0 there (valid address), and sc is forced to 0.
            int sA = __shfl(e, iA);
            float scA = (iA < m) ? __shfl(dsl, iA) * di : 0.f;
            uint2 vA = h64[(size_t)sA * 32 + k];
            a0 = fmaf(bf16lo(vA.x), scA, a0); a1 = fmaf(bf16hi(vA.x), scA, a1);
            a2 = fmaf(bf16lo(vA.y), scA, a2); a3 = fmaf(bf16hi(vA.y), scA, a3);
        }
    }
    // combine halves (both halves end with the full sum)
    a0 += __shfl_xor(a0, 32);
    a1 += __shfl_xor(a1, 32);
    a2 += __shfl_xor(a2, 32);
    a3 += __shfl_xor(a3, 32);
    if (half == 0) {
        if (bias) {
            float4 b = ((const float4*)bias)[k];
            a0 += b.x; a1 += b.y; a2 += b.z; a3 += b.w;
        }
        if (relu) {
            a0 = fmaxf(a0, 0.f); a1 = fmaxf(a1, 0.f);
            a2 = fmaxf(a2, 0.f); a3 = fmaxf(a3, 0.f);
        }
        uint2 o = {packbf2(a0, a1), packbf2(a2, a3)};
        ((uint2*)out)[(size_t)node * 32 + k] = o;
    }
}

extern "C" void kernel_launch(void* const* d_in, const int* in_sizes, int n_in,
                              void* d_out, int out_size, void* d_ws, size_t ws_size,
                              hipStream_t stream) {
    const float* x  = (const float*)d_in[0];
    const int*   ei = (const int*)d_in[1];
    const float* W1 = (const float*)d_in[2];
    const float* b1 = (const float*)d_in[3];
    const float* W2 = (const float*)d_in[4];
    const float* b2 = (const float*)d_in[5];
    const float* W3 = (const float*)d_in[6];
    const float* b3 = (const float*)d_in[7];
    int N = in_sizes[0] / 128;
    int E = in_sizes[1] / 2;
    const int* row = ei;
    const int* col = ei + E;
    int NB = (N + 255) >> 8;

    char* ws = (char*)d_ws;
    size_t off = 0;
    auto alloc = [&](size_t bytes) {
        void* p = ws + off;
        off += (bytes + 255) & ~(size_t)255;
        return p;
    };
    unsigned short* hA = (unsigned short*)alloc((size_t)N * 128 * 2);
    unsigned short* hB = (unsigned short*)alloc((size_t)N * 128 * 2);
    int*   esrc  = (int*)alloc((size_t)E * 4);
    int*   cptr  = (int*)alloc((size_t)N * 4);
    int*   cnt   = (int*)alloc((size_t)N * 4);
    float* dis   = (float*)alloc((size_t)N * 4);
    int*   bsum  = (int*)alloc(256 * 4);
    int*   bhist = (int*)alloc(512 * 4);
    int*   bbase = (int*)alloc(513 * 4);
    int*   bcur  = (int*)alloc(512 * 4);
    // binned staging (E*4B = 6.4 MB) aliases hB (25.6 MB): hB is first
    // written by agg1, long after k_fill2 consumed binned.
    unsigned* binned = (unsigned*)hB;

    // ---- CSR build (two-level counting sort) ----
    hipMemsetAsync(bhist, 0, 512 * 4, stream);
    k_bhist<<<256, 256, 0, stream>>>(col, E, NB, bhist);
    k_bscan<<<1, 512, 0, stream>>>(bhist, NB, E, bbase, bcur);
    k_bin2<<<256, 256, 0, stream>>>(row, col, E, bcur, binned);
    k_cntB<<<NB, 256, 0, stream>>>(binned, bbase, N, cnt);
    int B = (N + 1023) / 1024;
    k_bsum<<<B, 256, 0, stream>>>(cnt, N, bsum);
    k_sbsum<<<1, 128, 0, stream>>>(bsum, B);
    k_wptr<<<B, 256, 0, stream>>>(cnt, bsum, N, cptr, dis);
    k_fill2<<<NB, 256, 0, stream>>>(binned, bbase, cptr, N, esrc);

    // ---- layers ----
    int gb = (N + 63) / 64;
    int ab = (N + 3) / 4;
    k_gemm128_f32<<<gb, 256, 0, stream>>>(x, W1, hA, N);
    k_agg128<<<ab, 256, 0, stream>>>(hA, dis, cptr, cnt, esrc, b1, hB, 1, N);
    k_gemm128_bf16<<<gb, 256, 0, stream>>>(hB, W2, hA, N);
    k_agg128<<<ab, 256, 0, stream>>>(hA, dis, cptr, cnt, esrc, b2, hB, 1, N);
    k_agg128<<<ab, 256, 0, stream>>>(hB, dis, cptr, cnt, esrc, nullptr, hA, 0, N);
    k_gemm40f<<<gb, 320, 0, stream>>>(hA, W3, b3, (float*)d_out, N);
}

// Round 15
// 502.853 us; speedup vs baseline: 2.4596x; 1.0445x over previous
//
#include <hip/hip_runtime.h>
#include <hip/hip_bf16.h>
#include <math.h>

// ---------------------------------------------------------------------------
// 3-layer GCN, bf16 hidden activations (f32 accumulation everywhere).
// CSR build = two-level counting sort by 256-node bucket.
// Layer 3 reordered via linearity: agg(h@W3) == agg(h)@W3.
// agg128: half-wave edge split. gemm40f: bf16-packed LDS X tile (pad 69,
// conflict-free), register-partial softmax (no osm buffer).
// ---------------------------------------------------------------------------

__device__ inline float bfu(unsigned short s) {
    return __uint_as_float((unsigned)s << 16);
}
__device__ inline float bf16lo(unsigned u) { return __uint_as_float(u << 16); }
__device__ inline float bf16hi(unsigned u) { return __uint_as_float(u & 0xFFFF0000u); }
__device__ inline unsigned packbf2(float a, float b) {
    __hip_bfloat16 x = __float2bfloat16(a), y = __float2bfloat16(b);
    unsigned short ux = *(unsigned short*)&x, uy = *(unsigned short*)&y;
    return (unsigned)ux | ((unsigned)uy << 16);
}

// ---- bucket histogram ----
__global__ __launch_bounds__(256) void k_bhist(const int* __restrict__ col, int E,
                                               int NB, int* __restrict__ bhist) {
    __shared__ int h[512];
    for (int j = threadIdx.x; j < 512; j += 256) h[j] = 0;
    __syncthreads();
    int chunk = (E + gridDim.x - 1) / gridDim.x;
    int lo = blockIdx.x * chunk;
    int hi = min(lo + chunk, E);
    for (int i = lo + threadIdx.x; i < hi; i += 256)
        atomicAdd(&h[col[i] >> 8], 1);
    __syncthreads();
    for (int j = threadIdx.x; j < NB; j += 256) {
        int v = h[j];
        if (v) atomicAdd(&bhist[j], v);
    }
}

// ---- exclusive scan of bucket counts ----
__global__ __launch_bounds__(512) void k_bscan(const int* __restrict__ bhist,
                                               int NB, int E,
                                               int* __restrict__ bbase,
                                               int* __restrict__ bcur) {
    __shared__ int sm[512];
    int t = threadIdx.x;
    int v = (t < NB) ? bhist[t] : 0;
    sm[t] = v;
    __syncthreads();
    for (int off = 1; off < 512; off <<= 1) {
        int u = (t >= off) ? sm[t - off] : 0;
        __syncthreads();
        sm[t] += u;
        __syncthreads();
    }
    if (t < NB) {
        int ex = sm[t] - v;
        bbase[t] = ex;
        bcur[t] = ex;
    }
    if (t == 0) bbase[NB] = E;
}

// ---- two-level binning ----
__global__ __launch_bounds__(256) void k_bin2(const int* __restrict__ row,
                                              const int* __restrict__ col, int E,
                                              int* __restrict__ bcur,
                                              unsigned* __restrict__ binned) {
    __shared__ int h[512];
    __shared__ int base[512];
    int t = threadIdx.x;
    for (int j = t; j < 512; j += 256) h[j] = 0;
    __syncthreads();
    int chunk = (E + gridDim.x - 1) / gridDim.x;
    int lo = blockIdx.x * chunk;
    int hi = min(lo + chunk, E);
    for (int i = lo + t; i < hi; i += 256)
        atomicAdd(&h[col[i] >> 8], 1);
    __syncthreads();
    for (int j = t; j < 512; j += 256) {
        int c = h[j];
        base[j] = c ? atomicAdd(&bcur[j], c) : 0;
    }
    __syncthreads();
    for (int i = lo + t; i < hi; i += 256) {
        int r = row[i], c = col[i];
        int p = atomicAdd(&base[c >> 8], 1);
        binned[p] = (unsigned)r | ((unsigned)(c & 255) << 24);
    }
}

// ---- per-node counts ----
__global__ __launch_bounds__(256) void k_cntB(const unsigned* __restrict__ binned,
                                              const int* __restrict__ bbase,
                                              int N, int* __restrict__ cnt) {
    int b = blockIdx.x, t = threadIdx.x;
    __shared__ int sc[256];
    sc[t] = 0;
    __syncthreads();
    int lo = bbase[b], hi = bbase[b + 1];
    for (int i = lo + t; i < hi; i += 256)
        atomicAdd(&sc[binned[i] >> 24], 1);
    __syncthreads();
    int node = b * 256 + t;
    if (node < N) cnt[node] = sc[t];
}

// ---- scan stage 1 ----
__global__ __launch_bounds__(256) void k_bsum(const int* __restrict__ cnt, int N,
                                              int* __restrict__ bsum) {
    int t = threadIdx.x;
    int base = blockIdx.x * 1024 + t * 4;
    int s = 0;
    if (base + 3 < N) {
        int4 v = *(const int4*)(cnt + base);
        s = v.x + v.y + v.z + v.w;
    } else {
        for (int j = 0; j < 4; ++j)
            if (base + j < N) s += cnt[base + j];
    }
#pragma unroll
    for (int off = 32; off; off >>= 1) s += __shfl_xor(s, off);
    __shared__ int ws[4];
    int lane = t & 63, w = t >> 6;
    if (lane == 0) ws[w] = s;
    __syncthreads();
    if (t == 0) bsum[blockIdx.x] = ws[0] + ws[1] + ws[2] + ws[3];
}

// ---- scan stage 2 ----
__global__ __launch_bounds__(128) void k_sbsum(int* __restrict__ bsum, int B) {
    __shared__ int sm[128];
    int t = threadIdx.x;
    int v = (t < B) ? bsum[t] : 0;
    sm[t] = v;
    __syncthreads();
    for (int off = 1; off < 128; off <<= 1) {
        int u = (t >= off) ? sm[t - off] : 0;
        __syncthreads();
        sm[t] += u;
        __syncthreads();
    }
    if (t < B) bsum[t] = sm[t] - v;
}

// ---- scan stage 3: ptr/dis ----
__global__ __launch_bounds__(256) void k_wptr(const int* __restrict__ cnt,
                                              const int* __restrict__ bsum, int N,
                                              int* __restrict__ ptr,
                                              float* __restrict__ dis) {
    int t = threadIdx.x;
    int base = blockIdx.x * 1024 + t * 4;
    int c[4];
    int s = 0;
    if (base + 3 < N) {
        int4 v = *(const int4*)(cnt + base);
        c[0] = v.x; c[1] = v.y; c[2] = v.z; c[3] = v.w;
        s = v.x + v.y + v.z + v.w;
    } else {
#pragma unroll
        for (int j = 0; j < 4; ++j) {
            c[j] = (base + j < N) ? cnt[base + j] : 0;
            s += c[j];
        }
    }
    int lane = t & 63, w = t >> 6;
    int incl = s;
#pragma unroll
    for (int off = 1; off < 64; off <<= 1) {
        int u = __shfl_up(incl, off);
        if (lane >= off) incl += u;
    }
    __shared__ int wsum[4];
    if (lane == 63) wsum[w] = incl;
    __syncthreads();
    int run = bsum[blockIdx.x] + (incl - s);
    for (int j = 0; j < w; ++j) run += wsum[j];
#pragma unroll
    for (int j = 0; j < 4; ++j) {
        int i = base + j;
        if (i < N) {
            ptr[i] = run;
            dis[i] = rsqrtf((float)(c[j] + 1));
            run += c[j];
        }
    }
}

// ---- CSR fill ----
__global__ __launch_bounds__(256) void k_fill2(const unsigned* __restrict__ binned,
                                               const int* __restrict__ bbase,
                                               const int* __restrict__ ptr, int N,
                                               int* __restrict__ esrc) {
    int b = blockIdx.x, t = threadIdx.x;
    __shared__ int lc[256];
    int node = b * 256 + t;
    lc[t] = (node < N) ? ptr[node] : 0;
    __syncthreads();
    int lo = bbase[b], hi = bbase[b + 1];
    for (int i = lo + t; i < hi; i += 256) {
        unsigned e = binned[i];
        int p = atomicAdd(&lc[e >> 24], 1);
        esrc[p] = (int)(e & 0xFFFFFFu);
    }
}

// ---- GEMM layer1: X f32 [M][128] @ W f32 -> Y bf16 [M][128] ----
__global__ __launch_bounds__(256) void k_gemm128_f32(const float* __restrict__ X,
                                                     const float* __restrict__ W,
                                                     unsigned short* __restrict__ Y,
                                                     int M) {
    __shared__ float wsm[64 * 128];
    __shared__ float xs[64 * 68];
    int t = threadIdx.x;
    int row0 = blockIdx.x * 64;
    int cg = t & 15, rg = t >> 4;
    float acc[4][8];
#pragma unroll
    for (int a = 0; a < 4; ++a)
#pragma unroll
        for (int b = 0; b < 8; ++b) acc[a][b] = 0.f;

    for (int kp = 0; kp < 2; ++kp) {
        const float4* W4 = (const float4*)W;
        float4* wd = (float4*)wsm;
#pragma unroll
        for (int i = 0; i < 8; ++i) {
            int idx = t + i * 256;
            wd[idx] = W4[kp * 2048 + idx];
        }
        const float4* X4 = (const float4*)X;
#pragma unroll
        for (int i = 0; i < 4; ++i) {
            int idx = t + i * 256;
            int r = idx >> 4, c4 = idx & 15;
            float4 v = {0.f, 0.f, 0.f, 0.f};
            if (row0 + r < M) v = X4[(size_t)(row0 + r) * 32 + kp * 16 + c4];
            float* dst = &xs[r * 68 + c4 * 4];
            dst[0] = v.x; dst[1] = v.y; dst[2] = v.z; dst[3] = v.w;
        }
        __syncthreads();
#pragma unroll 4
        for (int k = 0; k < 64; ++k) {
            float a0 = xs[(rg * 4 + 0) * 68 + k];
            float a1 = xs[(rg * 4 + 1) * 68 + k];
            float a2 = xs[(rg * 4 + 2) * 68 + k];
            float a3 = xs[(rg * 4 + 3) * 68 + k];
            const float* wr = &wsm[k * 128 + cg * 8];
            float4 w0 = *(const float4*)wr;
            float4 w1 = *(const float4*)(wr + 4);
            float wv[8] = {w0.x, w0.y, w0.z, w0.w, w1.x, w1.y, w1.z, w1.w};
#pragma unroll
            for (int b = 0; b < 8; ++b) {
                acc[0][b] = fmaf(a0, wv[b], acc[0][b]);
                acc[1][b] = fmaf(a1, wv[b], acc[1][b]);
                acc[2][b] = fmaf(a2, wv[b], acc[2][b]);
                acc[3][b] = fmaf(a3, wv[b], acc[3][b]);
            }
        }
        __syncthreads();
    }
#pragma unroll
    for (int a = 0; a < 4; ++a) {
        int r = row0 + rg * 4 + a;
        if (r < M) {
            uint4 o;
            o.x = packbf2(acc[a][0], acc[a][1]);
            o.y = packbf2(acc[a][2], acc[a][3]);
            o.z = packbf2(acc[a][4], acc[a][5]);
            o.w = packbf2(acc[a][6], acc[a][7]);
            *(uint4*)&Y[(size_t)r * 128 + cg * 8] = o;
        }
    }
}

// ---- GEMM layer2: X bf16 [M][128] @ W f32 -> Y bf16 [M][128] ----
__global__ __launch_bounds__(256) void k_gemm128_bf16(const unsigned short* __restrict__ X,
                                                      const float* __restrict__ W,
                                                      unsigned short* __restrict__ Y,
                                                      int M) {
    __shared__ float wsm[64 * 128];
    __shared__ float xs[64 * 68];
    int t = threadIdx.x;
    int row0 = blockIdx.x * 64;
    int cg = t & 15, rg = t >> 4;
    float acc[4][8];
#pragma unroll
    for (int a = 0; a < 4; ++a)
#pragma unroll
        for (int b = 0; b < 8; ++b) acc[a][b] = 0.f;

    for (int kp = 0; kp < 2; ++kp) {
        const float4* W4 = (const float4*)W;
        float4* wd = (float4*)wsm;
#pragma unroll
        for (int i = 0; i < 8; ++i) {
            int idx = t + i * 256;
            wd[idx] = W4[kp * 2048 + idx];
        }
        const ushort4* X4 = (const ushort4*)X;
#pragma unroll
        for (int i = 0; i < 4; ++i) {
            int idx = t + i * 256;
            int r = idx >> 4, c4 = idx & 15;
            float v0 = 0.f, v1 = 0.f, v2 = 0.f, v3 = 0.f;
            if (row0 + r < M) {
                ushort4 v = X4[(size_t)(row0 + r) * 32 + kp * 16 + c4];
                v0 = bfu(v.x); v1 = bfu(v.y); v2 = bfu(v.z); v3 = bfu(v.w);
            }
            float* dst = &xs[r * 68 + c4 * 4];
            dst[0] = v0; dst[1] = v1; dst[2] = v2; dst[3] = v3;
        }
        __syncthreads();
#pragma unroll 4
        for (int k = 0; k < 64; ++k) {
            float a0 = xs[(rg * 4 + 0) * 68 + k];
            float a1 = xs[(rg * 4 + 1) * 68 + k];
            float a2 = xs[(rg * 4 + 2) * 68 + k];
            float a3 = xs[(rg * 4 + 3) * 68 + k];
            const float* wr = &wsm[k * 128 + cg * 8];
            float4 w0 = *(const float4*)wr;
            float4 w1 = *(const float4*)(wr + 4);
            float wv[8] = {w0.x, w0.y, w0.z, w0.w, w1.x, w1.y, w1.z, w1.w};
#pragma unroll
            for (int b = 0; b < 8; ++b) {
                acc[0][b] = fmaf(a0, wv[b], acc[0][b]);
                acc[1][b] = fmaf(a1, wv[b], acc[1][b]);
                acc[2][b] = fmaf(a2, wv[b], acc[2][b]);
                acc[3][b] = fmaf(a3, wv[b], acc[3][b]);
            }
        }
        __syncthreads();
    }
#pragma unroll
    for (int a = 0; a < 4; ++a) {
        int r = row0 + rg * 4 + a;
        if (r < M) {
            uint4 o;
            o.x = packbf2(acc[a][0], acc[a][1]);
            o.y = packbf2(acc[a][2], acc[a][3]);
            o.z = packbf2(acc[a][4], acc[a][5]);
            o.w = packbf2(acc[a][6], acc[a][7]);
            *(uint4*)&Y[(size_t)r * 128 + cg * 8] = o;
        }
    }
}

// ---- layer3 fused: Y = log_softmax(X bf16 [M][128] @ W3 [128][40] + b3) ----
// X tile kept as packed bf16 in LDS (pad 69 uints -> bank stride 5, no
// conflicts); softmax via register partials + tiny cross-cg LDS reduce.
__global__ __launch_bounds__(320) void k_gemm40f(const unsigned short* __restrict__ X,
                                                 const float* __restrict__ W,
                                                 const float* __restrict__ bias,
                                                 float* __restrict__ out, int M) {
    __shared__ float wsm[128 * 40];      // 20 KB
    __shared__ unsigned xs[64 * 69];     // 17.7 KB: 64 rows x 64 packed-bf16x2
    __shared__ float pm[5][64];
    __shared__ float ps[5][64];
    __shared__ float rm[64], rls[64];
    int t = threadIdx.x;
    int row0 = blockIdx.x * 64;
    for (int idx = t; idx < 128 * 40; idx += 320) wsm[idx] = W[idx];
    const uint2* X2 = (const uint2*)X;   // 4 bf16 per uint2
    for (int idx = t; idx < 2048; idx += 320) {
        int r = idx >> 5, c = idx & 31;  // c: uint2 index (8B)
        uint2 v = make_uint2(0u, 0u);
        if (row0 + r < M) v = X2[(size_t)(row0 + r) * 32 + c];
        xs[r * 69 + c * 2] = v.x;
        xs[r * 69 + c * 2 + 1] = v.y;
    }
    __syncthreads();
    int lane = t & 63, cg = t >> 6;      // cg 0..4, 8 cols each
    float acc[8];
#pragma unroll
    for (int b = 0; b < 8; ++b) acc[b] = 0.f;
    const unsigned* xrow = &xs[lane * 69];
#pragma unroll 4
    for (int kk = 0; kk < 64; ++kk) {
        unsigned u = xrow[kk];
        float a0 = bf16lo(u), a1 = bf16hi(u);
        const float* w0r = &wsm[(2 * kk) * 40 + cg * 8];
        const float* w1r = w0r + 40;
        float4 p0 = *(const float4*)w0r;
        float4 p1 = *(const float4*)(w0r + 4);
        float4 q0 = *(const float4*)w1r;
        float4 q1 = *(const float4*)(w1r + 4);
        acc[0] = fmaf(a1, q0.x, fmaf(a0, p0.x, acc[0]));
        acc[1] = fmaf(a1, q0.y, fmaf(a0, p0.y, acc[1]));
        acc[2] = fmaf(a1, q0.z, fmaf(a0, p0.z, acc[2]));
        acc[3] = fmaf(a1, q0.w, fmaf(a0, p0.w, acc[3]));
        acc[4] = fmaf(a1, q1.x, fmaf(a0, p1.x, acc[4]));
        acc[5] = fmaf(a1, q1.y, fmaf(a0, p1.y, acc[5]));
        acc[6] = fmaf(a1, q1.z, fmaf(a0, p1.z, acc[6]));
        acc[7] = fmaf(a1, q1.w, fmaf(a0, p1.w, acc[7]));
    }
#pragma unroll
    for (int b = 0; b < 8; ++b) acc[b] += bias[cg * 8 + b];
    // per-thread max of its 8 cols
    float lm = acc[0];
#pragma unroll
    for (int b = 1; b < 8; ++b) lm = fmaxf(lm, acc[b]);
    pm[cg][lane] = lm;
    __syncthreads();
    if (t < 64) {
        float m = pm[0][t];
#pragma unroll
        for (int c = 1; c < 5; ++c) m = fmaxf(m, pm[c][t]);
        rm[t] = m;
    }
    __syncthreads();
    float mrow = rm[lane];
    float lsum = 0.f;
#pragma unroll
    for (int b = 0; b < 8; ++b) lsum += expf(acc[b] - mrow);
    ps[cg][lane] = lsum;
    __syncthreads();
    if (t < 64) {
        float s = ps[0][t] + ps[1][t] + ps[2][t] + ps[3][t] + ps[4][t];
        rls[t] = logf(s);
    }
    __syncthreads();
    int r = row0 + lane;
    if (r < M) {
        float sub = mrow + rls[lane];
        float4* dst = (float4*)&out[(size_t)r * 40 + cg * 8];
        float4 o0 = {acc[0] - sub, acc[1] - sub, acc[2] - sub, acc[3] - sub};
        float4 o1 = {acc[4] - sub, acc[5] - sub, acc[6] - sub, acc[7] - sub};
        dst[0] = o0;
        dst[1] = o1;
    }
}

// ---- aggregation, 128 bf16: half-wave edge split, 8B/lane, x2 unroll ----
__global__ __launch_bounds__(256) void k_agg128(const unsigned short* __restrict__ h,
                                                const float* __restrict__ dis,
                                                const int* __restrict__ ptr,
                                                const int* __restrict__ cnt,
                                                const int* __restrict__ esrc,
                                                const float* __restrict__ bias,
                                                unsigned short* __restrict__ out,
                                                int relu, int N) {
    int node = blockIdx.x * 4 + (threadIdx.x >> 6);
    if (node >= N) return;
    int lane = threadIdx.x & 63;
    int half = lane >> 5;      // 0 or 1
    int k = lane & 31;         // uint2 index within row
    float di = dis[node];
    const uint2* h64 = (const uint2*)h;
    float a0 = 0.f, a1 = 0.f, a2 = 0.f, a3 = 0.f;
    if (half == 0) {           // self term on low half only
        uint2 su = h64[(size_t)node * 32 + k];
        float w = di * di;
        a0 = bf16lo(su.x) * w; a1 = bf16hi(su.x) * w;
        a2 = bf16lo(su.y) * w; a3 = bf16hi(su.y) * w;
    }
    int start = ptr[node], c = cnt[node];
    for (int base = 0; base < c; base += 64) {
        int m = min(64, c - base);
        int e = 0;
        float dsl = 0.f;
        if (lane < m) {
            e = esrc[start + base + lane];
            dsl = dis[e];
        }
        int jb = 0;
        for (; jb + 4 <= m; jb += 4) {
            int iA = jb + half, iB = jb + 2 + half;
            int sA = __shfl(e, iA), sB = __shfl(e, iB);
            float scA = __shfl(dsl, iA) * di;
            float scB = __shfl(dsl, iB) * di;
            uint2 vA = h64[(size_t)sA * 32 + k];
            uint2 vB = h64[(size_t)sB * 32 + k];
            a0 = fmaf(bf16lo(vA.x), scA, a0); a1 = fmaf(bf16hi(vA.x), scA, a1);
            a2 = fmaf(bf16lo(vA.y), scA, a2); a3 = fmaf(bf16hi(vA.y), scA, a3);
            a0 = fmaf(bf16lo(vB.x), scB, a0); a1 = fmaf(bf16hi(vB.x), scB, a1);
            a2 = fmaf(bf16lo(vB.y), scB, a2); a3 = fmaf(bf16hi(vB.y), scB, a3);
        }
        for (; jb < m; jb += 2) {
            int iA = jb + half;
            int sA = __shfl(e, iA);
            float scA = (iA < m) ? __shfl(dsl, iA) * di : 0.f;
            uint2 vA = h64[(size_t)sA * 32 + k];
            a0 = fmaf(bf16lo(vA.x), scA, a0); a1 = fmaf(bf16hi(vA.x), scA, a1);
            a2 = fmaf(bf16lo(vA.y), scA, a2); a3 = fmaf(bf16hi(vA.y), scA, a3);
        }
    }
    a0 += __shfl_xor(a0, 32);
    a1 += __shfl_xor(a1, 32);
    a2 += __shfl_xor(a2, 32);
    a3 += __shfl_xor(a3, 32);
    if (half == 0) {
        if (bias) {
            float4 b = ((const float4*)bias)[k];
            a0 += b.x; a1 += b.y; a2 += b.z; a3 += b.w;
        }
        if (relu) {
            a0 = fmaxf(a0, 0.f); a1 = fmaxf(a1, 0.f);
            a2 = fmaxf(a2, 0.f); a3 = fmaxf(a3, 0.f);
        }
        uint2 o = {packbf2(a0, a1), packbf2(a2, a3)};
        ((uint2*)out)[(size_t)node * 32 + k] = o;
    }
}

extern "C" void kernel_launch(void* const* d_in, const int* in_sizes, int n_in,
                              void* d_out, int out_size, void* d_ws, size_t ws_size,
                              hipStream_t stream) {
    const float* x  = (const float*)d_in[0];
    const int*   ei = (const int*)d_in[1];
    const float* W1 = (const float*)d_in[2];
    const float* b1 = (const float*)d_in[3];
    const float* W2 = (const float*)d_in[4];
    const float* b2 = (const float*)d_in[5];
    const float* W3 = (const float*)d_in[6];
    const float* b3 = (const float*)d_in[7];
    int N = in_sizes[0] / 128;
    int E = in_sizes[1] / 2;
    const int* row = ei;
    const int* col = ei + E;
    int NB = (N + 255) >> 8;

    char* ws = (char*)d_ws;
    size_t off = 0;
    auto alloc = [&](size_t bytes) {
        void* p = ws + off;
        off += (bytes + 255) & ~(size_t)255;
        return p;
    };
    unsigned short* hA = (unsigned short*)alloc((size_t)N * 128 * 2);
    unsigned short* hB = (unsigned short*)alloc((size_t)N * 128 * 2);
    int*   esrc  = (int*)alloc((size_t)E * 4);
    int*   cptr  = (int*)alloc((size_t)N * 4);
    int*   cnt   = (int*)alloc((size_t)N * 4);
    float* dis   = (float*)alloc((size_t)N * 4);
    int*   bsum  = (int*)alloc(256 * 4);
    int*   bhist = (int*)alloc(512 * 4);
    int*   bbase = (int*)alloc(513 * 4);
    int*   bcur  = (int*)alloc(512 * 4);
    // binned staging (E*4B = 6.4 MB) aliases hB (25.6 MB): hB is first
    // written by agg1, long after k_fill2 consumed binned.
    unsigned* binned = (unsigned*)hB;

    // ---- CSR build (two-level counting sort) ----
    hipMemsetAsync(bhist, 0, 512 * 4, stream);
    k_bhist<<<256, 256, 0, stream>>>(col, E, NB, bhist);
    k_bscan<<<1, 512, 0, stream>>>(bhist, NB, E, bbase, bcur);
    k_bin2<<<256, 256, 0, stream>>>(row, col, E, bcur, binned);
    k_cntB<<<NB, 256, 0, stream>>>(binned, bbase, N, cnt);
    int B = (N + 1023) / 1024;
    k_bsum<<<B, 256, 0, stream>>>(cnt, N, bsum);
    k_sbsum<<<1, 128, 0, stream>>>(bsum, B);
    k_wptr<<<B, 256, 0, stream>>>(cnt, bsum, N, cptr, dis);
    k_fill2<<<NB, 256, 0, stream>>>(binned, bbase, cptr, N, esrc);

    // ---- layers ----
    int gb = (N + 63) / 64;
    int ab = (N + 3) / 4;
    k_gemm128_f32<<<gb, 256, 0, stream>>>(x, W1, hA, N);
    k_agg128<<<ab, 256, 0, stream>>>(hA, dis, cptr, cnt, esrc, b1, hB, 1, N);
    k_gemm128_bf16<<<gb, 256, 0, stream>>>(hB, W2, hA, N);
    k_agg128<<<ab, 256, 0, stream>>>(hA, dis, cptr, cnt, esrc, b2, hB, 1, N);
    k_agg128<<<ab, 256, 0, stream>>>(hB, dis, cptr, cnt, esrc, nullptr, hA, 0, N);
    k_gemm40f<<<gb, 320, 0, stream>>>(hA, W3, b3, (float*)d_out, N);
}